// Round 6
// baseline (990.711 us; speedup 1.0000x reference)
//
#include <hip/hip_runtime.h>

// bPC SNN forward, 16 steps, B=128, dims 2048/4096/4096/512.
// v12: phase1 N-tile widened 32->64 (grid 512->256, 1 block/CU). Warm phase1
// was ~23.4 TB/s aggregate LDS-ingress from L2 (~68% of L2 ceiling); A-panels
// were 2/3 of that because each of 128 n-blocks re-staged them. N=64 halves
// A-traffic (515->343 MB/step). Same K-step/order -> bit-identical. mh-pair
// (n, n+64) same-XCD (64%8==0). phase2 = v9 (control). wprep 4-split.

#define DEVINL __device__ __forceinline__

using bf16x8 = __attribute__((ext_vector_type(8))) __bf16;
using f32x4  = __attribute__((ext_vector_type(4))) float;
using i32x4  = __attribute__((ext_vector_type(4))) int;
typedef unsigned char uchar;

static constexpr int BB = 128;
static constexpr int D0 = 2048, D1 = 4096, D2 = 4096, D3 = 512;
static constexpr int NSTEPS = 16;

struct Ctx {
  const float *x, *y, *W0, *W1, *W2, *V0, *V1, *V2;
  float *v1, *j1, *r1, *tr1, *v2, *j2, *r2, *tr2;
  float *zd, *zl, *xV0T, *yW2T;
  __bf16 *x_bf, *y_bf, *eg0_bf, *eg1_bf, *ed2_bf, *ed3_bf;
  uchar *s1_f8, *s2_f8, *WA8, *WB8;      // fp8 spikes + stacked fp8 weights
  __bf16 *W0t, *W1t, *V1t, *V2t, *V0n, *W2n;
  float *out;
};

DEVINL void gload16(const void* g, void* l) {
  __builtin_amdgcn_global_load_lds(
      (const __attribute__((address_space(1))) void*)g,
      (__attribute__((address_space(3))) void*)l, 16, 0, 0);
}
DEVINL uint32_t lds_off(const void* p) {
  return (uint32_t)(uintptr_t)(__attribute__((address_space(3))) const void*)p;
}
DEVINL bf16x8 dsr128(uint32_t addr) {
  i32x4 r;
  asm volatile("ds_read_b128 %0, %1" : "=v"(r) : "v"(addr));
  return __builtin_bit_cast(bf16x8, r);
}
DEVINL long dsr64(uint32_t addr) {
  long r;
  asm volatile("ds_read_b64 %0, %1" : "=v"(r) : "v"(addr));
  return r;
}

// ================= bf16 engines =================
struct Seg { const __bf16* A; unsigned ldA; const __bf16* W; unsigned ldW; int iters; };
struct SPtr { const __bf16 *a0, *a1, *w; };
struct SPtr2 { const __bf16 *a0, *a1, *w0, *w1; };

DEVINL SPtr mkptr(const Seg& s, int t) {
  int r = t >> 3;
  int u = ((t & 7) ^ (r & 7)) * 8;
  SPtr p;
  p.a0 = s.A + (size_t)r * s.ldA + u;
  p.a1 = s.A + (size_t)(r + 32) * s.ldA + u;
  p.w  = s.W + (size_t)r * s.ldW + u;
  return p;
}
DEVINL SPtr2 mkptr2(const Seg& s, int t) {
  int r = t >> 3;
  int u = ((t & 7) ^ (r & 7)) * 8;
  SPtr2 p;
  p.a0 = s.A + (size_t)r * s.ldA + u;
  p.a1 = s.A + (size_t)(r + 32) * s.ldA + u;
  p.w0 = s.W + (size_t)r * s.ldW + u;
  p.w1 = s.W + (size_t)(r + 32) * s.ldW + u;
  return p;
}

// ---- 32-wide engine (precomp) ----
DEVINL void run_gemm(const Seg* segs, int nIter, __bf16* lsA, __bf16* lsW,
                     int t, int wm, int wn, int l16, int lg, f32x4* acc) {
  const int seg0it = segs[0].iters;
  SPtr p = mkptr(segs[0], t);
  int nxt = 0;
  auto stage = [&](int s) {
    __bf16* bA = lsA + (s & 3) * 4096;
    __bf16* bW = lsW + (s & 3) * 2048;
    gload16(p.a0, bA + t * 8);
    gload16(p.a1, bA + 2048 + t * 8);
    gload16(p.w,  bW + t * 8);
    p.a0 += 64; p.a1 += 64; p.w += 64;
    if (++nxt == seg0it) p = mkptr(segs[1], t);
  };

  const int x7 = l16 & 7;
  uint32_t aB = lds_off(lsA), wB = lds_off(lsW);
  uint32_t aAd[2][2], wAd[2];
#pragma unroll
  for (int mt = 0; mt < 2; ++mt)
#pragma unroll
    for (int ks = 0; ks < 2; ++ks)
      aAd[mt][ks] = aB + (uint32_t)(wm * 32 + mt * 16 + l16) * 128u
                       + (uint32_t)(((ks * 4 + lg) ^ x7) * 16);
#pragma unroll
  for (int ks = 0; ks < 2; ++ks)
    wAd[ks] = wB + (uint32_t)(wn * 16 + l16) * 128u
                 + (uint32_t)(((ks * 4 + lg) ^ x7) * 16);

  auto compute = [&](int i) {
    uint32_t oa = (uint32_t)(i & 3) * 8192u, ow = (uint32_t)(i & 3) * 4096u;
    bf16x8 a00 = dsr128(aAd[0][0] + oa);
    bf16x8 a01 = dsr128(aAd[0][1] + oa);
    bf16x8 a10 = dsr128(aAd[1][0] + oa);
    bf16x8 a11 = dsr128(aAd[1][1] + oa);
    bf16x8 b0  = dsr128(wAd[0] + ow);
    bf16x8 b1  = dsr128(wAd[1] + ow);
    asm volatile("s_waitcnt lgkmcnt(0)" ::: "memory");
    __builtin_amdgcn_sched_barrier(0);
    __builtin_amdgcn_s_setprio(1);
    acc[0] = __builtin_amdgcn_mfma_f32_16x16x32_bf16(a00, b0, acc[0], 0, 0, 0);
    acc[1] = __builtin_amdgcn_mfma_f32_16x16x32_bf16(a10, b0, acc[1], 0, 0, 0);
    acc[0] = __builtin_amdgcn_mfma_f32_16x16x32_bf16(a01, b1, acc[0], 0, 0, 0);
    acc[1] = __builtin_amdgcn_mfma_f32_16x16x32_bf16(a11, b1, acc[1], 0, 0, 0);
    __builtin_amdgcn_s_setprio(0);
  };

  stage(0); stage(1); stage(2);
  for (int i = 0; i < nIter - 3; ++i) {
    asm volatile("s_waitcnt vmcnt(6)" ::: "memory");
    __builtin_amdgcn_s_barrier();
    stage(i + 3);
    compute(i);
  }
  asm volatile("s_waitcnt vmcnt(6)" ::: "memory");
  __builtin_amdgcn_s_barrier();
  compute(nIter - 3);
  asm volatile("s_waitcnt vmcnt(3)" ::: "memory");
  __builtin_amdgcn_s_barrier();
  compute(nIter - 2);
  asm volatile("s_waitcnt vmcnt(0)" ::: "memory");
  __builtin_amdgcn_s_barrier();
  compute(nIter - 1);
}

// ---- 64-wide engine (phase1 v12): tile 64M x 64N, K-step 64, 4 waves 2x2,
// wave 32x32, acc[4]. A and W both 64 rows (8KB/buf each); 4 bufs, 3 ahead,
// 4 DMAs/thread/stage, vmcnt 8/8/4/0. Same K-order as 32-wide -> bit-identical.
DEVINL void run_gemm64(const Seg* segs, int nIter, __bf16* lsA, __bf16* lsW,
                       int t, int wm, int wn, int l16, int lg, f32x4* acc) {
  const int seg0it = segs[0].iters;
  SPtr2 p = mkptr2(segs[0], t);
  int nxt = 0;
  auto stage = [&](int s) {
    __bf16* bA = lsA + (s & 3) * 4096;
    __bf16* bW = lsW + (s & 3) * 4096;
    gload16(p.a0, bA + t * 8);
    gload16(p.a1, bA + 2048 + t * 8);
    gload16(p.w0, bW + t * 8);
    gload16(p.w1, bW + 2048 + t * 8);
    p.a0 += 64; p.a1 += 64; p.w0 += 64; p.w1 += 64;
    if (++nxt == seg0it) p = mkptr2(segs[1], t);
  };

  const int x7 = l16 & 7;
  uint32_t aB = lds_off(lsA), wB = lds_off(lsW);
  uint32_t aAd[2][2], wAd[2][2];
#pragma unroll
  for (int mt = 0; mt < 2; ++mt)
#pragma unroll
    for (int ks = 0; ks < 2; ++ks)
      aAd[mt][ks] = aB + (uint32_t)(wm * 32 + mt * 16 + l16) * 128u
                       + (uint32_t)(((ks * 4 + lg) ^ x7) * 16);
#pragma unroll
  for (int nt = 0; nt < 2; ++nt)
#pragma unroll
    for (int ks = 0; ks < 2; ++ks)
      wAd[nt][ks] = wB + (uint32_t)(wn * 32 + nt * 16 + l16) * 128u
                       + (uint32_t)(((ks * 4 + lg) ^ x7) * 16);

  auto compute = [&](int i) {
    uint32_t o = (uint32_t)(i & 3) * 8192u;
    bf16x8 a00 = dsr128(aAd[0][0] + o);
    bf16x8 a01 = dsr128(aAd[0][1] + o);
    bf16x8 a10 = dsr128(aAd[1][0] + o);
    bf16x8 a11 = dsr128(aAd[1][1] + o);
    bf16x8 b00 = dsr128(wAd[0][0] + o);
    bf16x8 b01 = dsr128(wAd[0][1] + o);
    bf16x8 b10 = dsr128(wAd[1][0] + o);
    bf16x8 b11 = dsr128(wAd[1][1] + o);
    asm volatile("s_waitcnt lgkmcnt(0)" ::: "memory");
    __builtin_amdgcn_sched_barrier(0);
    __builtin_amdgcn_s_setprio(1);
    acc[0] = __builtin_amdgcn_mfma_f32_16x16x32_bf16(a00, b00, acc[0], 0, 0, 0);
    acc[1] = __builtin_amdgcn_mfma_f32_16x16x32_bf16(a00, b10, acc[1], 0, 0, 0);
    acc[2] = __builtin_amdgcn_mfma_f32_16x16x32_bf16(a10, b00, acc[2], 0, 0, 0);
    acc[3] = __builtin_amdgcn_mfma_f32_16x16x32_bf16(a10, b10, acc[3], 0, 0, 0);
    acc[0] = __builtin_amdgcn_mfma_f32_16x16x32_bf16(a01, b01, acc[0], 0, 0, 0);
    acc[1] = __builtin_amdgcn_mfma_f32_16x16x32_bf16(a01, b11, acc[1], 0, 0, 0);
    acc[2] = __builtin_amdgcn_mfma_f32_16x16x32_bf16(a11, b01, acc[2], 0, 0, 0);
    acc[3] = __builtin_amdgcn_mfma_f32_16x16x32_bf16(a11, b11, acc[3], 0, 0, 0);
    __builtin_amdgcn_s_setprio(0);
  };

  stage(0); stage(1); stage(2);
  for (int i = 0; i < nIter - 3; ++i) {
    asm volatile("s_waitcnt vmcnt(8)" ::: "memory");
    __builtin_amdgcn_s_barrier();
    stage(i + 3);
    compute(i);
  }
  asm volatile("s_waitcnt vmcnt(8)" ::: "memory");
  __builtin_amdgcn_s_barrier();
  compute(nIter - 3);
  asm volatile("s_waitcnt vmcnt(4)" ::: "memory");
  __builtin_amdgcn_s_barrier();
  compute(nIter - 2);
  asm volatile("s_waitcnt vmcnt(0)" ::: "memory");
  __builtin_amdgcn_s_barrier();
  compute(nIter - 1);
}

// ================= phase1 (bf16, 64-wide, z-balanced + XCD-paired) =================
// Grid 256: z = bx>>7 (z0 = 96-iter blocks first), idx = bx&127,
// mh = idx>>6, n0 = (idx&63)*64. Weight pair (n, n+64) -> same XCD.

__global__ __launch_bounds__(256, 1) void phase1_v12(Ctx c, float edsc) {
  __shared__ __align__(16) __bf16 lsA[4][4096];
  __shared__ __align__(16) __bf16 lsW[4][4096];
  int t = threadIdx.x, w = t >> 6, l = t & 63;
  int l16 = l & 15, lg = l >> 4, wm = w >> 1, wn = w & 1;
  int bx = blockIdx.x;
  int z = bx >> 7, idx = bx & 127;
  int mh = idx >> 6, n0 = (idx & 63) * 64;
  f32x4 acc[4];
  f32x4 z4 = {0.f, 0.f, 0.f, 0.f};
#pragma unroll
  for (int i = 0; i < 4; i++) acc[i] = z4;

  Seg segs[2]; int nIter, N;
  float *v, *j, *rf, *tr; const float* aux; const __bf16* buf; uchar* sf8;
  if (z == 0) {
    segs[0] = { c.ed2_bf + (size_t)mh * 64 * D2, (unsigned)D2, c.V1t + (size_t)n0 * D2, (unsigned)D2, 64 };
    segs[1] = { c.eg0_bf + (size_t)mh * 64 * D0, (unsigned)D0, c.W0t + (size_t)n0 * D0, (unsigned)D0, 32 };
    nIter = 96; N = D1;
    v = c.v1; j = c.j1; rf = c.r1; tr = c.tr1; buf = c.eg1_bf; aux = c.xV0T; sf8 = c.s1_f8;
  } else {
    segs[0] = { c.ed3_bf + (size_t)mh * 64 * D3, (unsigned)D3, c.V2t + (size_t)n0 * D3, (unsigned)D3, 8 };
    segs[1] = { c.eg1_bf + (size_t)mh * 64 * D1, (unsigned)D1, c.W1t + (size_t)n0 * D1, (unsigned)D1, 64 };
    nIter = 72; N = D2;
    v = c.v2; j = c.j2; rf = c.r2; tr = c.tr2; buf = c.ed2_bf; aux = c.yW2T; sf8 = c.s2_f8;
  }

  run_gemm64(segs, nIter, &lsA[0][0], &lsW[0][0], t, wm, wn, l16, lg, acc);

#pragma unroll
  for (int mt = 0; mt < 2; ++mt)
#pragma unroll
    for (int nt = 0; nt < 2; ++nt) {
      int n = n0 + wn * 32 + nt * 16 + l16;
#pragma unroll
      for (int r = 0; r < 4; ++r) {
        int b = mh * 64 + wm * 32 + mt * 16 + lg * 4 + r;
        size_t idx2 = (size_t)b * N + n;
        float to = tr[idx2];
        float ti = acc[mt * 2 + nt][r] - (float)buf[idx2] - edsc * (to - aux[idx2]);
        float jo = j[idx2];
        float jn = jo + 0.1f * (ti - jo);
        float ro = rf[idx2];
        float vo = v[idx2];
        bool refr = ro > 0.0f;
        float vn = refr ? vo : (vo + 0.05f * (jn - vo));
        float sp = (!refr && vn > 1.0f) ? 1.0f : 0.0f;
        if (sp != 0.0f) vn = 0.0f;
        float rn = fmaxf(ro - 1.0f, 0.0f);
        if (sp != 0.0f) rn = 2.0f;
        float tn = to - 0.05f * to + sp;
        v[idx2] = vn; j[idx2] = jn; rf[idx2] = rn; tr[idx2] = tn;
        sf8[idx2] = (sp != 0.0f) ? (uchar)0x38 : (uchar)0;  // fp8 e4m3: 1.0 / 0.0 exact
      }
    }
}

// ================= phase2 (fp8 engine, deep pipeline — v9) =================

__global__ __launch_bounds__(256, 2) void phase2_v9(Ctx c) {
  __shared__ __align__(16) uchar lsA[8][4096];
  __shared__ __align__(16) uchar lsW[8][4096];
  int t = threadIdx.x, w = t >> 6, l = t & 63;
  int l16 = l & 15, lg = l >> 4, wm = w >> 1, wn = w & 1;
  int g = blockIdx.x, mh = blockIdx.y;

  const uchar *A, *W; int n0; bool isA;
  if (g < 96) { isA = true;  A = c.s1_f8 + (size_t)mh * 64 * D1; W = c.WA8 + (size_t)g * 64 * 4096;        n0 = g * 64; }
  else        { isA = false; A = c.s2_f8 + (size_t)mh * 64 * D2; W = c.WB8 + (size_t)(g - 96) * 64 * 4096; n0 = (g - 96) * 64; }

  f32x4 acc[4];
  f32x4 z4 = {0.f, 0.f, 0.f, 0.f};
#pragma unroll
  for (int i = 0; i < 4; i++) acc[i] = z4;

  int row = t >> 2, u = t & 3;
  int su = (u ^ ((row >> 1) & 3)) * 16;
  const uchar* pA = A + (size_t)row * 4096 + su;
  const uchar* pW = W + (size_t)row * 4096 + su;
  uchar* dA = &lsA[0][0] + t * 16;
  uchar* dW = &lsW[0][0] + t * 16;
  auto stage = [&](int s) {
    gload16(pA, dA + (s & 7) * 4096);
    gload16(pW, dW + (s & 7) * 4096);
    pA += 64; pW += 64;
  };

  uint32_t aB = lds_off(lsA), wB = lds_off(lsW);
  uint32_t adA[2][2], adW[2][2];
#pragma unroll
  for (int mt = 0; mt < 2; ++mt)
#pragma unroll
    for (int ks = 0; ks < 2; ++ks) {
      int ra = wm * 32 + mt * 16 + l16;
      adA[mt][ks] = aB + (uint32_t)ra * 64u
                  + (uint32_t)((((ks * 2 + (lg >> 1)) ^ ((ra >> 1) & 3)) * 16) + (lg & 1) * 8);
    }
#pragma unroll
  for (int nt = 0; nt < 2; ++nt)
#pragma unroll
    for (int ks = 0; ks < 2; ++ks) {
      int rw = wn * 32 + nt * 16 + l16;
      adW[nt][ks] = wB + (uint32_t)rw * 64u
                  + (uint32_t)((((ks * 2 + (lg >> 1)) ^ ((rw >> 1) & 3)) * 16) + (lg & 1) * 8);
    }

  auto compute = [&](int i) {
    uint32_t off = (uint32_t)(i & 7) * 4096u;
    long a0  = dsr64(adA[0][0] + off);
    long a1  = dsr64(adA[1][0] + off);
    long b0  = dsr64(adW[0][0] + off);
    long b1  = dsr64(adW[1][0] + off);
    long a0b = dsr64(adA[0][1] + off);
    long a1b = dsr64(adA[1][1] + off);
    long b0b = dsr64(adW[0][1] + off);
    long b1b = dsr64(adW[1][1] + off);
    asm volatile("s_waitcnt lgkmcnt(0)" ::: "memory");
    __builtin_amdgcn_sched_barrier(0);
    __builtin_amdgcn_s_setprio(1);
    acc[0] = __builtin_amdgcn_mfma_f32_16x16x32_fp8_fp8(a0,  b0,  acc[0], 0, 0, 0);
    acc[1] = __builtin_amdgcn_mfma_f32_16x16x32_fp8_fp8(a0,  b1,  acc[1], 0, 0, 0);
    acc[2] = __builtin_amdgcn_mfma_f32_16x16x32_fp8_fp8(a1,  b0,  acc[2], 0, 0, 0);
    acc[3] = __builtin_amdgcn_mfma_f32_16x16x32_fp8_fp8(a1,  b1,  acc[3], 0, 0, 0);
    acc[0] = __builtin_amdgcn_mfma_f32_16x16x32_fp8_fp8(a0b, b0b, acc[0], 0, 0, 0);
    acc[1] = __builtin_amdgcn_mfma_f32_16x16x32_fp8_fp8(a0b, b1b, acc[1], 0, 0, 0);
    acc[2] = __builtin_amdgcn_mfma_f32_16x16x32_fp8_fp8(a1b, b0b, acc[2], 0, 0, 0);
    acc[3] = __builtin_amdgcn_mfma_f32_16x16x32_fp8_fp8(a1b, b1b, acc[3], 0, 0, 0);
    __builtin_amdgcn_s_setprio(0);
  };

  const int nIter = 64;
  stage(0); stage(1); stage(2); stage(3); stage(4); stage(5);
  for (int i = 0; i < nIter - 6; ++i) {
    asm volatile("s_waitcnt vmcnt(10)" ::: "memory");
    __builtin_amdgcn_s_barrier();
    stage(i + 6);
    compute(i);
  }
  asm volatile("s_waitcnt vmcnt(10)" ::: "memory");
  __builtin_amdgcn_s_barrier();
  compute(nIter - 6);
  asm volatile("s_waitcnt vmcnt(8)" ::: "memory");
  __builtin_amdgcn_s_barrier();
  compute(nIter - 5);
  asm volatile("s_waitcnt vmcnt(6)" ::: "memory");
  __builtin_amdgcn_s_barrier();
  compute(nIter - 4);
  asm volatile("s_waitcnt vmcnt(4)" ::: "memory");
  __builtin_amdgcn_s_barrier();
  compute(nIter - 3);
  asm volatile("s_waitcnt vmcnt(2)" ::: "memory");
  __builtin_amdgcn_s_barrier();
  compute(nIter - 2);
  asm volatile("s_waitcnt vmcnt(0)" ::: "memory");
  __builtin_amdgcn_s_barrier();
  compute(nIter - 1);

#pragma unroll
  for (int mt = 0; mt < 2; ++mt)
#pragma unroll
    for (int nt = 0; nt < 2; ++nt) {
      int nn = n0 + wn * 32 + nt * 16 + l16;
#pragma unroll
      for (int r = 0; r < 4; ++r) {
        int b = mh * 64 + wm * 32 + mt * 16 + lg * 4 + r;
        float av = acc[mt * 2 + nt][r];
        if (isA) {
          if (nn < 2048) {            // mode 0: eg0 (+ zd update)
            size_t idx = (size_t)b * D0 + nn;
            float zo = c.zd[idx]; float zn = zo - 0.1f * zo + c.x[idx];
            c.zd[idx] = zn;
            c.eg0_bf[idx] = (__bf16)(0.5f * (zn - av));
          } else {                    // mode 2: ed2
            size_t idx = (size_t)b * D2 + (nn - 2048);
            c.ed2_bf[idx] = (__bf16)(0.5f * (c.tr2[idx] - av));
          }
        } else {
          if (nn < 4096) {            // mode 1: eg1
            size_t idx = (size_t)b * D1 + nn;
            c.eg1_bf[idx] = (__bf16)(0.5f * (c.tr1[idx] - av));
          } else {                    // mode 3: ed3 (+ zl update, output)
            size_t idx = (size_t)b * D3 + (nn - 4096);
            float zo = c.zl[idx]; float zn = zo - 0.1f * zo + c.y[idx];
            c.zl[idx] = zn;
            float e = 0.5f * (zn - av);
            c.out[idx] = e; c.ed3_bf[idx] = (__bf16)e;
          }
        }
      }
    }
}

// ================= precomp (bf16 DMA engine, runs once) =================

__global__ __launch_bounds__(256, 2) void precomp_v6(Ctx c) {
  __shared__ __align__(16) __bf16 lsA[4][4096];
  __shared__ __align__(16) __bf16 lsW[4][2048];
  int t = threadIdx.x, w = t >> 6, l = t & 63;
  int l16 = l & 15, lg = l >> 4, wm = w >> 1, wn = w & 1;
  int n0 = blockIdx.x * 32, mh = blockIdx.y;
  f32x4 acc[2];
  f32x4 z4 = {0.f, 0.f, 0.f, 0.f};
  acc[0] = z4; acc[1] = z4;

  Seg segs[2]; int nIter, N; float* outp;
  if (blockIdx.z == 0) {
    segs[0] = { c.x_bf + (size_t)mh * 64 * D0, (unsigned)D0, c.V0n + (size_t)n0 * D0, (unsigned)D0, 32 };
    nIter = 32; N = D1; outp = c.xV0T;
  } else {
    segs[0] = { c.y_bf + (size_t)mh * 64 * D3, (unsigned)D3, c.W2n + (size_t)n0 * D3, (unsigned)D3, 8 };
    nIter = 8; N = D2; outp = c.yW2T;
  }
  segs[1] = segs[0];

  run_gemm(segs, nIter, &lsA[0][0], &lsW[0][0], t, wm, wn, l16, lg, acc);

  int n = n0 + wn * 16 + l16;
#pragma unroll
  for (int mt = 0; mt < 2; ++mt)
#pragma unroll
    for (int r = 0; r < 4; ++r) {
      int b = mh * 64 + wm * 32 + mt * 16 + lg * 4 + r;
      outp[(size_t)b * N + n] = acc[mt][r];
    }
}

// ================= one-shot prep (split into 4 launches via g0) =================

__global__ __launch_bounds__(256) void wprep_kernel(Ctx c, int g0) {
  __shared__ float ls[64][65];
  int g = blockIdx.x + g0;
  const float* src; __bf16* tp = nullptr; uchar* n8 = nullptr; __bf16* nb = nullptr; int R, C;
  if (g < 2048)       { src = c.W0; n8 = c.WA8;                         tp = c.W0t; R = D0; C = D1; }
  else if (g < 6144)  { g -= 2048;  src = c.W1; n8 = c.WB8;             tp = c.W1t; R = D1; C = D2; }
  else if (g < 10240) { g -= 6144;  src = c.V1; n8 = c.WA8 + (size_t)2048 * 4096; tp = c.V1t; R = D2; C = D1; }
  else if (g < 10752) { g -= 10240; src = c.V2; n8 = c.WB8 + (size_t)4096 * 4096; tp = c.V2t; R = D3; C = D2; }
  else if (g < 12800) { g -= 10752; src = c.V0; nb = c.V0n; R = D1; C = D0; }
  else                { g -= 12800; src = c.W2; nb = c.W2n; R = D2; C = D3; }
  int tpr = C / 64;
  int r0 = (g / tpr) * 64, c0 = (g % tpr) * 64;
  int t = threadIdx.x, r = t >> 2, q = t & 3;

  const float4* s4 = reinterpret_cast<const float4*>(src + (size_t)(r0 + r) * C + c0 + q * 16);
  if (n8) {
    int pk[4];
#pragma unroll
    for (int i = 0; i < 4; i++) {
      float4 v = s4[i];
      ls[r][q * 16 + i * 4 + 0] = v.x; ls[r][q * 16 + i * 4 + 1] = v.y;
      ls[r][q * 16 + i * 4 + 2] = v.z; ls[r][q * 16 + i * 4 + 3] = v.w;
      int wd = __builtin_amdgcn_cvt_pk_fp8_f32(v.x, v.y, 0, false);
      wd = __builtin_amdgcn_cvt_pk_fp8_f32(v.z, v.w, wd, true);
      pk[i] = wd;
    }
    int4 pv; pv.x = pk[0]; pv.y = pk[1]; pv.z = pk[2]; pv.w = pk[3];
    *reinterpret_cast<int4*>(n8 + (size_t)(r0 + r) * C + c0 + q * 16) = pv;
    __syncthreads();
    union { __bf16 h[16]; int4 qq[2]; } wv;
#pragma unroll
    for (int i = 0; i < 16; i++) wv.h[i] = (__bf16)ls[q * 16 + i][r];
    int4* dt = reinterpret_cast<int4*>(tp + (size_t)(c0 + r) * R + r0 + q * 16);
    dt[0] = wv.qq[0]; dt[1] = wv.qq[1];
  } else {
    union { __bf16 h[16]; int4 qq[2]; } uu;
#pragma unroll
    for (int i = 0; i < 4; i++) {
      float4 v = s4[i];
      uu.h[i * 4 + 0] = (__bf16)v.x; uu.h[i * 4 + 1] = (__bf16)v.y;
      uu.h[i * 4 + 2] = (__bf16)v.z; uu.h[i * 4 + 3] = (__bf16)v.w;
    }
    int4* dn = reinterpret_cast<int4*>(nb + (size_t)(r0 + r) * C + c0 + q * 16);
    dn[0] = uu.qq[0]; dn[1] = uu.qq[1];
  }
}

// cast x,y -> bf16 AND step-0 "phase2" (s=tr=0): zd=x, zl=y, eg0=.5x, ed3=.5y.
__global__ __launch_bounds__(256) void castinit_kernel(Ctx c) {
  int i = blockIdx.x * 256 + threadIdx.x;
  const int NX = BB * D0 / 4;
  union { __bf16 h[4]; uint2 u; } p, q;
  if (i < NX) {
    float4 xv = reinterpret_cast<const float4*>(c.x)[i];
    reinterpret_cast<float4*>(c.zd)[i] = xv;
    p.h[0] = (__bf16)xv.x; p.h[1] = (__bf16)xv.y; p.h[2] = (__bf16)xv.z; p.h[3] = (__bf16)xv.w;
    reinterpret_cast<uint2*>(c.x_bf)[i] = p.u;
    q.h[0] = (__bf16)(0.5f * xv.x); q.h[1] = (__bf16)(0.5f * xv.y);
    q.h[2] = (__bf16)(0.5f * xv.z); q.h[3] = (__bf16)(0.5f * xv.w);
    reinterpret_cast<uint2*>(c.eg0_bf)[i] = q.u;
  } else {
    int k = i - NX;
    float4 yv = reinterpret_cast<const float4*>(c.y)[k];
    reinterpret_cast<float4*>(c.zl)[k] = yv;
    p.h[0] = (__bf16)yv.x; p.h[1] = (__bf16)yv.y; p.h[2] = (__bf16)yv.z; p.h[3] = (__bf16)yv.w;
    reinterpret_cast<uint2*>(c.y_bf)[k] = p.u;
    q.h[0] = (__bf16)(0.5f * yv.x); q.h[1] = (__bf16)(0.5f * yv.y);
    q.h[2] = (__bf16)(0.5f * yv.z); q.h[3] = (__bf16)(0.5f * yv.w);
    reinterpret_cast<uint2*>(c.ed3_bf)[k] = q.u;
  }
}

// ================= host =================

extern "C" void kernel_launch(void* const* d_in, const int* in_sizes, int n_in,
                              void* d_out, int out_size, void* d_ws, size_t ws_size,
                              hipStream_t stream) {
  Ctx c;
  c.x  = (const float*)d_in[0];
  c.y  = (const float*)d_in[1];
  c.W0 = (const float*)d_in[2];
  c.W1 = (const float*)d_in[3];
  c.W2 = (const float*)d_in[4];
  c.V0 = (const float*)d_in[5];
  c.V1 = (const float*)d_in[6];
  c.V2 = (const float*)d_in[7];
  c.out = (float*)d_out;

  char* p = (char*)d_ws;
  auto af = [&](size_t n) -> float* { float* r = (float*)p; p += ((n * 4 + 255) & ~(size_t)255); return r; };
  auto ah = [&](size_t n) -> __bf16* { __bf16* r = (__bf16*)p; p += ((n * 2 + 255) & ~(size_t)255); return r; };
  auto au = [&](size_t n) -> uchar* { uchar* r = (uchar*)p; p += ((n + 255) & ~(size_t)255); return r; };

  const size_t S1 = (size_t)BB * D1;
  // --- zero-initialized state (memset span) ---
  c.v1 = af(S1); c.j1 = af(S1); c.r1 = af(S1); c.tr1 = af(S1);
  c.v2 = af(S1); c.j2 = af(S1); c.r2 = af(S1); c.tr2 = af(S1);
  c.eg1_bf = ah(S1); c.ed2_bf = ah(S1);
  size_t zero_bytes = (size_t)(p - (char*)d_ws);
  // --- written-before-read buffers ---
  c.zd = af((size_t)BB * D0); c.zl = af((size_t)BB * D3);
  c.xV0T = af(S1); c.yW2T = af(S1);
  c.x_bf = ah((size_t)BB * D0); c.y_bf = ah((size_t)BB * D3);
  c.eg0_bf = ah((size_t)BB * D0); c.ed3_bf = ah((size_t)BB * D3);
  c.s1_f8 = au(S1); c.s2_f8 = au(S1);
  // --- weight copies ---
  c.W0t = ah((size_t)D0 * D1); c.W1t = ah((size_t)D1 * D2); c.V1t = ah((size_t)D2 * D1); c.V2t = ah((size_t)D3 * D2);
  c.V0n = ah((size_t)D1 * D0); c.W2n = ah((size_t)D2 * D3);
  c.WA8 = au((size_t)(D0 + D2) * 4096);   // [W0; V1] rows, K=4096
  c.WB8 = au((size_t)(D1 + D3) * 4096);   // [W1; V2] rows, K=4096

  hipMemsetAsync(d_ws, 0, zero_bytes, stream);
  castinit_kernel<<<320, 256, 0, stream>>>(c);
  wprep_kernel<<<2048, 256, 0, stream>>>(c, 0);       // W0
  wprep_kernel<<<4096, 256, 0, stream>>>(c, 2048);    // W1
  wprep_kernel<<<4096, 256, 0, stream>>>(c, 6144);    // V1
  wprep_kernel<<<3072, 256, 0, stream>>>(c, 10240);   // V2 + V0 + W2
  precomp_v6<<<dim3(128, 2, 2), 256, 0, stream>>>(c);

  for (int s = 1; s < NSTEPS; s++) {
    phase1_v12<<<256, 256, 0, stream>>>(c, 0.5f);
    phase2_v9<<<dim3(168, 2), 256, 0, stream>>>(c);
  }
}

// Round 7
// 887.170 us; speedup vs baseline: 1.1167x; 1.1167x over previous
//
#include <hip/hip_runtime.h>

// bPC SNN forward, 16 steps, B=128, dims 2048/4096/4096/512.
// v13: phase1 reverted to v11 exactly (908us config: 32-wide tiles, grid 512,
// 2 blocks/CU, z-balance 96+72 per CU, XCD-paired weights). v12's N=64 broke
// both TLP and z-balance -> +82us; reverted.
// Single variable: phase2 BK 64->128 bytes (iters 64->32). v9 proved the
// ~500cyc/iter is not uncovered latency; MFMA+LDS is ~150cyc -> the rest is
// per-iter sync overhead, halved by doubling BK. Same K order -> bit-identical.
// LDS 4buf x 16KB = 64KB, still 2 blocks/CU. vmcnt 8/8/4/0 (4 DMA/stage).

#define DEVINL __device__ __forceinline__

using bf16x8 = __attribute__((ext_vector_type(8))) __bf16;
using f32x4  = __attribute__((ext_vector_type(4))) float;
using i32x4  = __attribute__((ext_vector_type(4))) int;
typedef unsigned char uchar;

static constexpr int BB = 128;
static constexpr int D0 = 2048, D1 = 4096, D2 = 4096, D3 = 512;
static constexpr int NSTEPS = 16;

struct Ctx {
  const float *x, *y, *W0, *W1, *W2, *V0, *V1, *V2;
  float *v1, *j1, *r1, *tr1, *v2, *j2, *r2, *tr2;
  float *zd, *zl, *xV0T, *yW2T;
  __bf16 *x_bf, *y_bf, *eg0_bf, *eg1_bf, *ed2_bf, *ed3_bf;
  uchar *s1_f8, *s2_f8, *WA8, *WB8;      // fp8 spikes + stacked fp8 weights
  __bf16 *W0t, *W1t, *V1t, *V2t, *V0n, *W2n;
  float *out;
};

DEVINL void gload16(const void* g, void* l) {
  __builtin_amdgcn_global_load_lds(
      (const __attribute__((address_space(1))) void*)g,
      (__attribute__((address_space(3))) void*)l, 16, 0, 0);
}
DEVINL uint32_t lds_off(const void* p) {
  return (uint32_t)(uintptr_t)(__attribute__((address_space(3))) const void*)p;
}
DEVINL bf16x8 dsr128(uint32_t addr) {
  i32x4 r;
  asm volatile("ds_read_b128 %0, %1" : "=v"(r) : "v"(addr));
  return __builtin_bit_cast(bf16x8, r);
}
DEVINL long dsr64(uint32_t addr) {
  long r;
  asm volatile("ds_read_b64 %0, %1" : "=v"(r) : "v"(addr));
  return r;
}

// ================= bf16 engine (r5, proven) =================
struct Seg { const __bf16* A; unsigned ldA; const __bf16* W; unsigned ldW; int iters; };
struct SPtr { const __bf16 *a0, *a1, *w; };

DEVINL SPtr mkptr(const Seg& s, int t) {
  int r = t >> 3;
  int u = ((t & 7) ^ (r & 7)) * 8;
  SPtr p;
  p.a0 = s.A + (size_t)r * s.ldA + u;
  p.a1 = s.A + (size_t)(r + 32) * s.ldA + u;
  p.w  = s.W + (size_t)r * s.ldW + u;
  return p;
}

DEVINL void run_gemm(const Seg* segs, int nIter, __bf16* lsA, __bf16* lsW,
                     int t, int wm, int wn, int l16, int lg, f32x4* acc) {
  const int seg0it = segs[0].iters;
  SPtr p = mkptr(segs[0], t);
  int nxt = 0;
  auto stage = [&](int s) {
    __bf16* bA = lsA + (s & 3) * 4096;
    __bf16* bW = lsW + (s & 3) * 2048;
    gload16(p.a0, bA + t * 8);
    gload16(p.a1, bA + 2048 + t * 8);
    gload16(p.w,  bW + t * 8);
    p.a0 += 64; p.a1 += 64; p.w += 64;
    if (++nxt == seg0it) p = mkptr(segs[1], t);
  };

  const int x7 = l16 & 7;
  uint32_t aB = lds_off(lsA), wB = lds_off(lsW);
  uint32_t aAd[2][2], wAd[2];
#pragma unroll
  for (int mt = 0; mt < 2; ++mt)
#pragma unroll
    for (int ks = 0; ks < 2; ++ks)
      aAd[mt][ks] = aB + (uint32_t)(wm * 32 + mt * 16 + l16) * 128u
                       + (uint32_t)(((ks * 4 + lg) ^ x7) * 16);
#pragma unroll
  for (int ks = 0; ks < 2; ++ks)
    wAd[ks] = wB + (uint32_t)(wn * 16 + l16) * 128u
                 + (uint32_t)(((ks * 4 + lg) ^ x7) * 16);

  auto compute = [&](int i) {
    uint32_t oa = (uint32_t)(i & 3) * 8192u, ow = (uint32_t)(i & 3) * 4096u;
    bf16x8 a00 = dsr128(aAd[0][0] + oa);
    bf16x8 a01 = dsr128(aAd[0][1] + oa);
    bf16x8 a10 = dsr128(aAd[1][0] + oa);
    bf16x8 a11 = dsr128(aAd[1][1] + oa);
    bf16x8 b0  = dsr128(wAd[0] + ow);
    bf16x8 b1  = dsr128(wAd[1] + ow);
    asm volatile("s_waitcnt lgkmcnt(0)" ::: "memory");
    __builtin_amdgcn_sched_barrier(0);
    __builtin_amdgcn_s_setprio(1);
    acc[0] = __builtin_amdgcn_mfma_f32_16x16x32_bf16(a00, b0, acc[0], 0, 0, 0);
    acc[1] = __builtin_amdgcn_mfma_f32_16x16x32_bf16(a10, b0, acc[1], 0, 0, 0);
    acc[0] = __builtin_amdgcn_mfma_f32_16x16x32_bf16(a01, b1, acc[0], 0, 0, 0);
    acc[1] = __builtin_amdgcn_mfma_f32_16x16x32_bf16(a11, b1, acc[1], 0, 0, 0);
    __builtin_amdgcn_s_setprio(0);
  };

  stage(0); stage(1); stage(2);
  for (int i = 0; i < nIter - 3; ++i) {
    asm volatile("s_waitcnt vmcnt(6)" ::: "memory");
    __builtin_amdgcn_s_barrier();
    stage(i + 3);
    compute(i);
  }
  asm volatile("s_waitcnt vmcnt(6)" ::: "memory");
  __builtin_amdgcn_s_barrier();
  compute(nIter - 3);
  asm volatile("s_waitcnt vmcnt(3)" ::: "memory");
  __builtin_amdgcn_s_barrier();
  compute(nIter - 2);
  asm volatile("s_waitcnt vmcnt(0)" ::: "memory");
  __builtin_amdgcn_s_barrier();
  compute(nIter - 1);
}

// ================= phase1 (bf16, DMA engine, z-balanced + XCD-paired — v11) =================
// z = bx>>8 (96-iter z=0 blocks first, 72-iter z=1 second: one of each per CU).
// mh = idx>>7, n0 = idx&127: weight pair (n, n+128) -> same XCD -> L2 hit.

__global__ __launch_bounds__(256, 2) void phase1_v11(Ctx c, float edsc) {
  __shared__ __align__(16) __bf16 lsA[4][4096];
  __shared__ __align__(16) __bf16 lsW[4][2048];
  int t = threadIdx.x, w = t >> 6, l = t & 63;
  int l16 = l & 15, lg = l >> 4, wm = w >> 1, wn = w & 1;
  int bx = blockIdx.x;
  int z = bx >> 8, idx = bx & 255;
  int mh = idx >> 7, n0 = (idx & 127) * 32;
  f32x4 acc[2];
  f32x4 z4 = {0.f, 0.f, 0.f, 0.f};
  acc[0] = z4; acc[1] = z4;

  Seg segs[2]; int nIter, N;
  float *v, *j, *rf, *tr; const float* aux; const __bf16* buf; uchar* sf8;
  if (z == 0) {
    segs[0] = { c.ed2_bf + (size_t)mh * 64 * D2, (unsigned)D2, c.V1t + (size_t)n0 * D2, (unsigned)D2, 64 };
    segs[1] = { c.eg0_bf + (size_t)mh * 64 * D0, (unsigned)D0, c.W0t + (size_t)n0 * D0, (unsigned)D0, 32 };
    nIter = 96; N = D1;
    v = c.v1; j = c.j1; rf = c.r1; tr = c.tr1; buf = c.eg1_bf; aux = c.xV0T; sf8 = c.s1_f8;
  } else {
    segs[0] = { c.ed3_bf + (size_t)mh * 64 * D3, (unsigned)D3, c.V2t + (size_t)n0 * D3, (unsigned)D3, 8 };
    segs[1] = { c.eg1_bf + (size_t)mh * 64 * D1, (unsigned)D1, c.W1t + (size_t)n0 * D1, (unsigned)D1, 64 };
    nIter = 72; N = D2;
    v = c.v2; j = c.j2; rf = c.r2; tr = c.tr2; buf = c.ed2_bf; aux = c.yW2T; sf8 = c.s2_f8;
  }

  run_gemm(segs, nIter, &lsA[0][0], &lsW[0][0], t, wm, wn, l16, lg, acc);

  int n = n0 + wn * 16 + l16;
#pragma unroll
  for (int mt = 0; mt < 2; ++mt) {
#pragma unroll
    for (int r = 0; r < 4; ++r) {
      int b = mh * 64 + wm * 32 + mt * 16 + lg * 4 + r;
      size_t idx2 = (size_t)b * N + n;
      float to = tr[idx2];
      float ti = acc[mt][r] - (float)buf[idx2] - edsc * (to - aux[idx2]);
      float jo = j[idx2];
      float jn = jo + 0.1f * (ti - jo);
      float ro = rf[idx2];
      float vo = v[idx2];
      bool refr = ro > 0.0f;
      float vn = refr ? vo : (vo + 0.05f * (jn - vo));
      float sp = (!refr && vn > 1.0f) ? 1.0f : 0.0f;
      if (sp != 0.0f) vn = 0.0f;
      float rn = fmaxf(ro - 1.0f, 0.0f);
      if (sp != 0.0f) rn = 2.0f;
      float tn = to - 0.05f * to + sp;
      v[idx2] = vn; j[idx2] = jn; rf[idx2] = rn; tr[idx2] = tn;
      sf8[idx2] = (sp != 0.0f) ? (uchar)0x38 : (uchar)0;  // fp8 e4m3: 1.0 / 0.0 exact
    }
  }
}

// ================= phase2 (fp8 engine, BK=128: half the barriers) =================
// Block tile 64(M) x 64(N), BK=128 bytes (K=4096 -> 32 iters); 4 waves 2x2,
// wave 32x32. LDS: 4 buf x (A 8KB + W 8KB) = 64KB (2 blocks/CU). Each buffer
// = two 64B halves (half1 at +4096), same swizzle per half. 4 DMAs/thread/
// stage, 3 ahead, vmcnt 8/8/4/0, one barrier per 128B of K. K-order of the
// 32-wide MFMA slices is unchanged -> bit-identical to v9.

__global__ __launch_bounds__(256, 2) void phase2_v13(Ctx c) {
  __shared__ __align__(16) uchar lsA[4][8192];
  __shared__ __align__(16) uchar lsW[4][8192];
  int t = threadIdx.x, w = t >> 6, l = t & 63;
  int l16 = l & 15, lg = l >> 4, wm = w >> 1, wn = w & 1;
  int g = blockIdx.x, mh = blockIdx.y;

  const uchar *A, *W; int n0; bool isA;
  if (g < 96) { isA = true;  A = c.s1_f8 + (size_t)mh * 64 * D1; W = c.WA8 + (size_t)g * 64 * 4096;        n0 = g * 64; }
  else        { isA = false; A = c.s2_f8 + (size_t)mh * 64 * D2; W = c.WB8 + (size_t)(g - 96) * 64 * 4096; n0 = (g - 96) * 64; }

  f32x4 acc[4];
  f32x4 z4 = {0.f, 0.f, 0.f, 0.f};
#pragma unroll
  for (int i = 0; i < 4; i++) acc[i] = z4;

  int row = t >> 2, u = t & 3;
  int su = (u ^ ((row >> 1) & 3)) * 16;
  const uchar* pA = A + (size_t)row * 4096 + su;   // half0; half1 at +64
  const uchar* pW = W + (size_t)row * 4096 + su;
  uchar* dA = &lsA[0][0] + t * 16;                 // half0; half1 at +4096
  uchar* dW = &lsW[0][0] + t * 16;
  auto stage = [&](int s) {
    uint32_t o = (uint32_t)(s & 3) * 8192u;
    gload16(pA,      dA + o);
    gload16(pA + 64, dA + o + 4096);
    gload16(pW,      dW + o);
    gload16(pW + 64, dW + o + 4096);
    pA += 128; pW += 128;
  };

  uint32_t aB = lds_off(lsA), wB = lds_off(lsW);
  uint32_t adA[2][2], adW[2][2];
#pragma unroll
  for (int mt = 0; mt < 2; ++mt)
#pragma unroll
    for (int ks = 0; ks < 2; ++ks) {
      int ra = wm * 32 + mt * 16 + l16;
      adA[mt][ks] = aB + (uint32_t)ra * 64u
                  + (uint32_t)((((ks * 2 + (lg >> 1)) ^ ((ra >> 1) & 3)) * 16) + (lg & 1) * 8);
    }
#pragma unroll
  for (int nt = 0; nt < 2; ++nt)
#pragma unroll
    for (int ks = 0; ks < 2; ++ks) {
      int rw = wn * 32 + nt * 16 + l16;
      adW[nt][ks] = wB + (uint32_t)rw * 64u
                  + (uint32_t)((((ks * 2 + (lg >> 1)) ^ ((rw >> 1) & 3)) * 16) + (lg & 1) * 8);
    }

  auto compute = [&](int i) {
    uint32_t off = (uint32_t)(i & 3) * 8192u;
    long a0h0  = dsr64(adA[0][0] + off);
    long a1h0  = dsr64(adA[1][0] + off);
    long b0h0  = dsr64(adW[0][0] + off);
    long b1h0  = dsr64(adW[1][0] + off);
    long a0h0b = dsr64(adA[0][1] + off);
    long a1h0b = dsr64(adA[1][1] + off);
    long b0h0b = dsr64(adW[0][1] + off);
    long b1h0b = dsr64(adW[1][1] + off);
    long a0h1  = dsr64(adA[0][0] + off + 4096);
    long a1h1  = dsr64(adA[1][0] + off + 4096);
    long b0h1  = dsr64(adW[0][0] + off + 4096);
    long b1h1  = dsr64(adW[1][0] + off + 4096);
    long a0h1b = dsr64(adA[0][1] + off + 4096);
    long a1h1b = dsr64(adA[1][1] + off + 4096);
    long b0h1b = dsr64(adW[0][1] + off + 4096);
    long b1h1b = dsr64(adW[1][1] + off + 4096);
    asm volatile("s_waitcnt lgkmcnt(0)" ::: "memory");
    __builtin_amdgcn_sched_barrier(0);
    __builtin_amdgcn_s_setprio(1);
    // K order: half0 ks0, half0 ks1, half1 ks0, half1 ks1 — same as v9's
    // sequential 64B iterations -> bit-identical accumulation.
    acc[0] = __builtin_amdgcn_mfma_f32_16x16x32_fp8_fp8(a0h0,  b0h0,  acc[0], 0, 0, 0);
    acc[1] = __builtin_amdgcn_mfma_f32_16x16x32_fp8_fp8(a0h0,  b1h0,  acc[1], 0, 0, 0);
    acc[2] = __builtin_amdgcn_mfma_f32_16x16x32_fp8_fp8(a1h0,  b0h0,  acc[2], 0, 0, 0);
    acc[3] = __builtin_amdgcn_mfma_f32_16x16x32_fp8_fp8(a1h0,  b1h0,  acc[3], 0, 0, 0);
    acc[0] = __builtin_amdgcn_mfma_f32_16x16x32_fp8_fp8(a0h0b, b0h0b, acc[0], 0, 0, 0);
    acc[1] = __builtin_amdgcn_mfma_f32_16x16x32_fp8_fp8(a0h0b, b1h0b, acc[1], 0, 0, 0);
    acc[2] = __builtin_amdgcn_mfma_f32_16x16x32_fp8_fp8(a1h0b, b0h0b, acc[2], 0, 0, 0);
    acc[3] = __builtin_amdgcn_mfma_f32_16x16x32_fp8_fp8(a1h0b, b1h0b, acc[3], 0, 0, 0);
    acc[0] = __builtin_amdgcn_mfma_f32_16x16x32_fp8_fp8(a0h1,  b0h1,  acc[0], 0, 0, 0);
    acc[1] = __builtin_amdgcn_mfma_f32_16x16x32_fp8_fp8(a0h1,  b1h1,  acc[1], 0, 0, 0);
    acc[2] = __builtin_amdgcn_mfma_f32_16x16x32_fp8_fp8(a1h1,  b0h1,  acc[2], 0, 0, 0);
    acc[3] = __builtin_amdgcn_mfma_f32_16x16x32_fp8_fp8(a1h1,  b1h1,  acc[3], 0, 0, 0);
    acc[0] = __builtin_amdgcn_mfma_f32_16x16x32_fp8_fp8(a0h1b, b0h1b, acc[0], 0, 0, 0);
    acc[1] = __builtin_amdgcn_mfma_f32_16x16x32_fp8_fp8(a0h1b, b1h1b, acc[1], 0, 0, 0);
    acc[2] = __builtin_amdgcn_mfma_f32_16x16x32_fp8_fp8(a1h1b, b0h1b, acc[2], 0, 0, 0);
    acc[3] = __builtin_amdgcn_mfma_f32_16x16x32_fp8_fp8(a1h1b, b1h1b, acc[3], 0, 0, 0);
    __builtin_amdgcn_s_setprio(0);
  };

  const int nIter = 32;
  stage(0); stage(1); stage(2);
  for (int i = 0; i < nIter - 3; ++i) {
    asm volatile("s_waitcnt vmcnt(8)" ::: "memory");
    __builtin_amdgcn_s_barrier();
    stage(i + 3);
    compute(i);
  }
  asm volatile("s_waitcnt vmcnt(8)" ::: "memory");
  __builtin_amdgcn_s_barrier();
  compute(nIter - 3);
  asm volatile("s_waitcnt vmcnt(4)" ::: "memory");
  __builtin_amdgcn_s_barrier();
  compute(nIter - 2);
  asm volatile("s_waitcnt vmcnt(0)" ::: "memory");
  __builtin_amdgcn_s_barrier();
  compute(nIter - 1);

#pragma unroll
  for (int mt = 0; mt < 2; ++mt)
#pragma unroll
    for (int nt = 0; nt < 2; ++nt) {
      int nn = n0 + wn * 32 + nt * 16 + l16;
#pragma unroll
      for (int r = 0; r < 4; ++r) {
        int b = mh * 64 + wm * 32 + mt * 16 + lg * 4 + r;
        float av = acc[mt * 2 + nt][r];
        if (isA) {
          if (nn < 2048) {            // mode 0: eg0 (+ zd update)
            size_t idx = (size_t)b * D0 + nn;
            float zo = c.zd[idx]; float zn = zo - 0.1f * zo + c.x[idx];
            c.zd[idx] = zn;
            c.eg0_bf[idx] = (__bf16)(0.5f * (zn - av));
          } else {                    // mode 2: ed2
            size_t idx = (size_t)b * D2 + (nn - 2048);
            c.ed2_bf[idx] = (__bf16)(0.5f * (c.tr2[idx] - av));
          }
        } else {
          if (nn < 4096) {            // mode 1: eg1
            size_t idx = (size_t)b * D1 + nn;
            c.eg1_bf[idx] = (__bf16)(0.5f * (c.tr1[idx] - av));
          } else {                    // mode 3: ed3 (+ zl update, output)
            size_t idx = (size_t)b * D3 + (nn - 4096);
            float zo = c.zl[idx]; float zn = zo - 0.1f * zo + c.y[idx];
            c.zl[idx] = zn;
            float e = 0.5f * (zn - av);
            c.out[idx] = e; c.ed3_bf[idx] = (__bf16)e;
          }
        }
      }
    }
}

// ================= precomp (bf16 DMA engine, runs once) =================

__global__ __launch_bounds__(256, 2) void precomp_v6(Ctx c) {
  __shared__ __align__(16) __bf16 lsA[4][4096];
  __shared__ __align__(16) __bf16 lsW[4][2048];
  int t = threadIdx.x, w = t >> 6, l = t & 63;
  int l16 = l & 15, lg = l >> 4, wm = w >> 1, wn = w & 1;
  int n0 = blockIdx.x * 32, mh = blockIdx.y;
  f32x4 acc[2];
  f32x4 z4 = {0.f, 0.f, 0.f, 0.f};
  acc[0] = z4; acc[1] = z4;

  Seg segs[2]; int nIter, N; float* outp;
  if (blockIdx.z == 0) {
    segs[0] = { c.x_bf + (size_t)mh * 64 * D0, (unsigned)D0, c.V0n + (size_t)n0 * D0, (unsigned)D0, 32 };
    nIter = 32; N = D1; outp = c.xV0T;
  } else {
    segs[0] = { c.y_bf + (size_t)mh * 64 * D3, (unsigned)D3, c.W2n + (size_t)n0 * D3, (unsigned)D3, 8 };
    nIter = 8; N = D2; outp = c.yW2T;
  }
  segs[1] = segs[0];

  run_gemm(segs, nIter, &lsA[0][0], &lsW[0][0], t, wm, wn, l16, lg, acc);

  int n = n0 + wn * 16 + l16;
#pragma unroll
  for (int mt = 0; mt < 2; ++mt)
#pragma unroll
    for (int r = 0; r < 4; ++r) {
      int b = mh * 64 + wm * 32 + mt * 16 + lg * 4 + r;
      outp[(size_t)b * N + n] = acc[mt][r];
    }
}

// ================= one-shot prep (split into 4 launches via g0) =================

__global__ __launch_bounds__(256) void wprep_kernel(Ctx c, int g0) {
  __shared__ float ls[64][65];
  int g = blockIdx.x + g0;
  const float* src; __bf16* tp = nullptr; uchar* n8 = nullptr; __bf16* nb = nullptr; int R, C;
  if (g < 2048)       { src = c.W0; n8 = c.WA8;                         tp = c.W0t; R = D0; C = D1; }
  else if (g < 6144)  { g -= 2048;  src = c.W1; n8 = c.WB8;             tp = c.W1t; R = D1; C = D2; }
  else if (g < 10240) { g -= 6144;  src = c.V1; n8 = c.WA8 + (size_t)2048 * 4096; tp = c.V1t; R = D2; C = D1; }
  else if (g < 10752) { g -= 10240; src = c.V2; n8 = c.WB8 + (size_t)4096 * 4096; tp = c.V2t; R = D3; C = D2; }
  else if (g < 12800) { g -= 10752; src = c.V0; nb = c.V0n; R = D1; C = D0; }
  else                { g -= 12800; src = c.W2; nb = c.W2n; R = D2; C = D3; }
  int tpr = C / 64;
  int r0 = (g / tpr) * 64, c0 = (g % tpr) * 64;
  int t = threadIdx.x, r = t >> 2, q = t & 3;

  const float4* s4 = reinterpret_cast<const float4*>(src + (size_t)(r0 + r) * C + c0 + q * 16);
  if (n8) {
    int pk[4];
#pragma unroll
    for (int i = 0; i < 4; i++) {
      float4 v = s4[i];
      ls[r][q * 16 + i * 4 + 0] = v.x; ls[r][q * 16 + i * 4 + 1] = v.y;
      ls[r][q * 16 + i * 4 + 2] = v.z; ls[r][q * 16 + i * 4 + 3] = v.w;
      int wd = __builtin_amdgcn_cvt_pk_fp8_f32(v.x, v.y, 0, false);
      wd = __builtin_amdgcn_cvt_pk_fp8_f32(v.z, v.w, wd, true);
      pk[i] = wd;
    }
    int4 pv; pv.x = pk[0]; pv.y = pk[1]; pv.z = pk[2]; pv.w = pk[3];
    *reinterpret_cast<int4*>(n8 + (size_t)(r0 + r) * C + c0 + q * 16) = pv;
    __syncthreads();
    union { __bf16 h[16]; int4 qq[2]; } wv;
#pragma unroll
    for (int i = 0; i < 16; i++) wv.h[i] = (__bf16)ls[q * 16 + i][r];
    int4* dt = reinterpret_cast<int4*>(tp + (size_t)(c0 + r) * R + r0 + q * 16);
    dt[0] = wv.qq[0]; dt[1] = wv.qq[1];
  } else {
    union { __bf16 h[16]; int4 qq[2]; } uu;
#pragma unroll
    for (int i = 0; i < 4; i++) {
      float4 v = s4[i];
      uu.h[i * 4 + 0] = (__bf16)v.x; uu.h[i * 4 + 1] = (__bf16)v.y;
      uu.h[i * 4 + 2] = (__bf16)v.z; uu.h[i * 4 + 3] = (__bf16)v.w;
    }
    int4* dn = reinterpret_cast<int4*>(nb + (size_t)(r0 + r) * C + c0 + q * 16);
    dn[0] = uu.qq[0]; dn[1] = uu.qq[1];
  }
}

// cast x,y -> bf16 AND step-0 "phase2" (s=tr=0): zd=x, zl=y, eg0=.5x, ed3=.5y.
__global__ __launch_bounds__(256) void castinit_kernel(Ctx c) {
  int i = blockIdx.x * 256 + threadIdx.x;
  const int NX = BB * D0 / 4;
  union { __bf16 h[4]; uint2 u; } p, q;
  if (i < NX) {
    float4 xv = reinterpret_cast<const float4*>(c.x)[i];
    reinterpret_cast<float4*>(c.zd)[i] = xv;
    p.h[0] = (__bf16)xv.x; p.h[1] = (__bf16)xv.y; p.h[2] = (__bf16)xv.z; p.h[3] = (__bf16)xv.w;
    reinterpret_cast<uint2*>(c.x_bf)[i] = p.u;
    q.h[0] = (__bf16)(0.5f * xv.x); q.h[1] = (__bf16)(0.5f * xv.y);
    q.h[2] = (__bf16)(0.5f * xv.z); q.h[3] = (__bf16)(0.5f * xv.w);
    reinterpret_cast<uint2*>(c.eg0_bf)[i] = q.u;
  } else {
    int k = i - NX;
    float4 yv = reinterpret_cast<const float4*>(c.y)[k];
    reinterpret_cast<float4*>(c.zl)[k] = yv;
    p.h[0] = (__bf16)yv.x; p.h[1] = (__bf16)yv.y; p.h[2] = (__bf16)yv.z; p.h[3] = (__bf16)yv.w;
    reinterpret_cast<uint2*>(c.y_bf)[k] = p.u;
    q.h[0] = (__bf16)(0.5f * yv.x); q.h[1] = (__bf16)(0.5f * yv.y);
    q.h[2] = (__bf16)(0.5f * yv.z); q.h[3] = (__bf16)(0.5f * yv.w);
    reinterpret_cast<uint2*>(c.ed3_bf)[k] = q.u;
  }
}

// ================= host =================

extern "C" void kernel_launch(void* const* d_in, const int* in_sizes, int n_in,
                              void* d_out, int out_size, void* d_ws, size_t ws_size,
                              hipStream_t stream) {
  Ctx c;
  c.x  = (const float*)d_in[0];
  c.y  = (const float*)d_in[1];
  c.W0 = (const float*)d_in[2];
  c.W1 = (const float*)d_in[3];
  c.W2 = (const float*)d_in[4];
  c.V0 = (const float*)d_in[5];
  c.V1 = (const float*)d_in[6];
  c.V2 = (const float*)d_in[7];
  c.out = (float*)d_out;

  char* p = (char*)d_ws;
  auto af = [&](size_t n) -> float* { float* r = (float*)p; p += ((n * 4 + 255) & ~(size_t)255); return r; };
  auto ah = [&](size_t n) -> __bf16* { __bf16* r = (__bf16*)p; p += ((n * 2 + 255) & ~(size_t)255); return r; };
  auto au = [&](size_t n) -> uchar* { uchar* r = (uchar*)p; p += ((n + 255) & ~(size_t)255); return r; };

  const size_t S1 = (size_t)BB * D1;
  // --- zero-initialized state (memset span) ---
  c.v1 = af(S1); c.j1 = af(S1); c.r1 = af(S1); c.tr1 = af(S1);
  c.v2 = af(S1); c.j2 = af(S1); c.r2 = af(S1); c.tr2 = af(S1);
  c.eg1_bf = ah(S1); c.ed2_bf = ah(S1);
  size_t zero_bytes = (size_t)(p - (char*)d_ws);
  // --- written-before-read buffers ---
  c.zd = af((size_t)BB * D0); c.zl = af((size_t)BB * D3);
  c.xV0T = af(S1); c.yW2T = af(S1);
  c.x_bf = ah((size_t)BB * D0); c.y_bf = ah((size_t)BB * D3);
  c.eg0_bf = ah((size_t)BB * D0); c.ed3_bf = ah((size_t)BB * D3);
  c.s1_f8 = au(S1); c.s2_f8 = au(S1);
  // --- weight copies ---
  c.W0t = ah((size_t)D0 * D1); c.W1t = ah((size_t)D1 * D2); c.V1t = ah((size_t)D2 * D1); c.V2t = ah((size_t)D3 * D2);
  c.V0n = ah((size_t)D1 * D0); c.W2n = ah((size_t)D2 * D3);
  c.WA8 = au((size_t)(D0 + D2) * 4096);   // [W0; V1] rows, K=4096
  c.WB8 = au((size_t)(D1 + D3) * 4096);   // [W1; V2] rows, K=4096

  hipMemsetAsync(d_ws, 0, zero_bytes, stream);
  castinit_kernel<<<320, 256, 0, stream>>>(c);
  wprep_kernel<<<2048, 256, 0, stream>>>(c, 0);       // W0
  wprep_kernel<<<4096, 256, 0, stream>>>(c, 2048);    // W1
  wprep_kernel<<<4096, 256, 0, stream>>>(c, 6144);    // V1
  wprep_kernel<<<3072, 256, 0, stream>>>(c, 10240);   // V2 + V0 + W2
  precomp_v6<<<dim3(128, 2, 2), 256, 0, stream>>>(c);

  for (int s = 1; s < NSTEPS; s++) {
    phase1_v11<<<512, 256, 0, stream>>>(c, 0.5f);
    phase2_v13<<<dim3(168, 2), 256, 0, stream>>>(c);
  }
}

// Round 8
// 860.942 us; speedup vs baseline: 1.1507x; 1.0305x over previous
//
#include <hip/hip_runtime.h>

// bPC SNN forward, 16 steps, B=128, dims 2048/4096/4096/512.
// v14: phase1 BK 64->128 (96/72 -> 48/36 iters; halves barrier+sync overhead,
// the same lever that won in phase2 v13). 3-buf x 24KB = 72KB LDS, 2 blocks/CU
// (144KB <= 160KB), 6 DMA/stage, vmcnt 6/6/0. K-order per output unchanged ->
// bit-identical. wprep launches reordered so phase1-step1 inputs (V1t, W0t)
// are written LAST -> L3-resident for the cold step. phase2 = v13 (control).

#define DEVINL __device__ __forceinline__

using bf16x8 = __attribute__((ext_vector_type(8))) __bf16;
using f32x4  = __attribute__((ext_vector_type(4))) float;
using i32x4  = __attribute__((ext_vector_type(4))) int;
typedef unsigned char uchar;

static constexpr int BB = 128;
static constexpr int D0 = 2048, D1 = 4096, D2 = 4096, D3 = 512;
static constexpr int NSTEPS = 16;

struct Ctx {
  const float *x, *y, *W0, *W1, *W2, *V0, *V1, *V2;
  float *v1, *j1, *r1, *tr1, *v2, *j2, *r2, *tr2;
  float *zd, *zl, *xV0T, *yW2T;
  __bf16 *x_bf, *y_bf, *eg0_bf, *eg1_bf, *ed2_bf, *ed3_bf;
  uchar *s1_f8, *s2_f8, *WA8, *WB8;      // fp8 spikes + stacked fp8 weights
  __bf16 *W0t, *W1t, *V1t, *V2t, *V0n, *W2n;
  float *out;
};

DEVINL void gload16(const void* g, void* l) {
  __builtin_amdgcn_global_load_lds(
      (const __attribute__((address_space(1))) void*)g,
      (__attribute__((address_space(3))) void*)l, 16, 0, 0);
}
DEVINL uint32_t lds_off(const void* p) {
  return (uint32_t)(uintptr_t)(__attribute__((address_space(3))) const void*)p;
}
DEVINL bf16x8 dsr128(uint32_t addr) {
  i32x4 r;
  asm volatile("ds_read_b128 %0, %1" : "=v"(r) : "v"(addr));
  return __builtin_bit_cast(bf16x8, r);
}
DEVINL long dsr64(uint32_t addr) {
  long r;
  asm volatile("ds_read_b64 %0, %1" : "=v"(r) : "v"(addr));
  return r;
}

// ================= bf16 engines =================
struct Seg { const __bf16* A; unsigned ldA; const __bf16* W; unsigned ldW; int iters; };
struct SPtr { const __bf16 *a0, *a1, *w; };

DEVINL SPtr mkptr(const Seg& s, int t) {
  int r = t >> 3;
  int u = ((t & 7) ^ (r & 7)) * 8;
  SPtr p;
  p.a0 = s.A + (size_t)r * s.ldA + u;
  p.a1 = s.A + (size_t)(r + 32) * s.ldA + u;
  p.w  = s.W + (size_t)r * s.ldW + u;
  return p;
}

// ---- BK=64 engine (precomp) ----
DEVINL void run_gemm(const Seg* segs, int nIter, __bf16* lsA, __bf16* lsW,
                     int t, int wm, int wn, int l16, int lg, f32x4* acc) {
  const int seg0it = segs[0].iters;
  SPtr p = mkptr(segs[0], t);
  int nxt = 0;
  auto stage = [&](int s) {
    __bf16* bA = lsA + (s & 3) * 4096;
    __bf16* bW = lsW + (s & 3) * 2048;
    gload16(p.a0, bA + t * 8);
    gload16(p.a1, bA + 2048 + t * 8);
    gload16(p.w,  bW + t * 8);
    p.a0 += 64; p.a1 += 64; p.w += 64;
    if (++nxt == seg0it) p = mkptr(segs[1], t);
  };

  const int x7 = l16 & 7;
  uint32_t aB = lds_off(lsA), wB = lds_off(lsW);
  uint32_t aAd[2][2], wAd[2];
#pragma unroll
  for (int mt = 0; mt < 2; ++mt)
#pragma unroll
    for (int ks = 0; ks < 2; ++ks)
      aAd[mt][ks] = aB + (uint32_t)(wm * 32 + mt * 16 + l16) * 128u
                       + (uint32_t)(((ks * 4 + lg) ^ x7) * 16);
#pragma unroll
  for (int ks = 0; ks < 2; ++ks)
    wAd[ks] = wB + (uint32_t)(wn * 16 + l16) * 128u
                 + (uint32_t)(((ks * 4 + lg) ^ x7) * 16);

  auto compute = [&](int i) {
    uint32_t oa = (uint32_t)(i & 3) * 8192u, ow = (uint32_t)(i & 3) * 4096u;
    bf16x8 a00 = dsr128(aAd[0][0] + oa);
    bf16x8 a01 = dsr128(aAd[0][1] + oa);
    bf16x8 a10 = dsr128(aAd[1][0] + oa);
    bf16x8 a11 = dsr128(aAd[1][1] + oa);
    bf16x8 b0  = dsr128(wAd[0] + ow);
    bf16x8 b1  = dsr128(wAd[1] + ow);
    asm volatile("s_waitcnt lgkmcnt(0)" ::: "memory");
    __builtin_amdgcn_sched_barrier(0);
    __builtin_amdgcn_s_setprio(1);
    acc[0] = __builtin_amdgcn_mfma_f32_16x16x32_bf16(a00, b0, acc[0], 0, 0, 0);
    acc[1] = __builtin_amdgcn_mfma_f32_16x16x32_bf16(a10, b0, acc[1], 0, 0, 0);
    acc[0] = __builtin_amdgcn_mfma_f32_16x16x32_bf16(a01, b1, acc[0], 0, 0, 0);
    acc[1] = __builtin_amdgcn_mfma_f32_16x16x32_bf16(a11, b1, acc[1], 0, 0, 0);
    __builtin_amdgcn_s_setprio(0);
  };

  stage(0); stage(1); stage(2);
  for (int i = 0; i < nIter - 3; ++i) {
    asm volatile("s_waitcnt vmcnt(6)" ::: "memory");
    __builtin_amdgcn_s_barrier();
    stage(i + 3);
    compute(i);
  }
  asm volatile("s_waitcnt vmcnt(6)" ::: "memory");
  __builtin_amdgcn_s_barrier();
  compute(nIter - 3);
  asm volatile("s_waitcnt vmcnt(3)" ::: "memory");
  __builtin_amdgcn_s_barrier();
  compute(nIter - 2);
  asm volatile("s_waitcnt vmcnt(0)" ::: "memory");
  __builtin_amdgcn_s_barrier();
  compute(nIter - 1);
}

// ---- BK=128 engine (phase1 v14): 3 buffers (A 16KB + W 8KB each), 2 ahead.
// Per stage: 6 DMAs (A half0 r0-31/r32-63, A half1 same, W half0/half1).
// Per compute: 12 ds_read_b128 + 8 MFMA. K order = two consecutive BK=64
// iters (half0 ks0,ks1; half1 ks0,ks1) -> bit-identical accumulation.
DEVINL void run_gemm128(const Seg* segs, int nIter, __bf16* lsA, __bf16* lsW,
                        int t, int wm, int wn, int l16, int lg, f32x4* acc) {
  const int seg0it = segs[0].iters;   // in BK=128 units
  SPtr p = mkptr(segs[0], t);
  int nxt = 0;
  auto stage = [&](int buf) {
    __bf16* bA = lsA + buf * 8192;
    __bf16* bW = lsW + buf * 4096;
    gload16(p.a0,      bA + t * 8);          // K half0, rows 0..31
    gload16(p.a1,      bA + 2048 + t * 8);   // K half0, rows 32..63
    gload16(p.a0 + 64, bA + 4096 + t * 8);   // K half1, rows 0..31
    gload16(p.a1 + 64, bA + 6144 + t * 8);   // K half1, rows 32..63
    gload16(p.w,       bW + t * 8);          // W half0
    gload16(p.w + 64,  bW + 2048 + t * 8);   // W half1
    p.a0 += 128; p.a1 += 128; p.w += 128;
    if (++nxt == seg0it) p = mkptr(segs[1], t);
  };

  const int x7 = l16 & 7;
  uint32_t aB = lds_off(lsA), wB = lds_off(lsW);
  uint32_t aAd[2][2], wAd[2];
#pragma unroll
  for (int mt = 0; mt < 2; ++mt)
#pragma unroll
    for (int ks = 0; ks < 2; ++ks)
      aAd[mt][ks] = aB + (uint32_t)(wm * 32 + mt * 16 + l16) * 128u
                       + (uint32_t)(((ks * 4 + lg) ^ x7) * 16);
#pragma unroll
  for (int ks = 0; ks < 2; ++ks)
    wAd[ks] = wB + (uint32_t)(wn * 16 + l16) * 128u
                 + (uint32_t)(((ks * 4 + lg) ^ x7) * 16);

  auto compute = [&](int buf) {
    uint32_t oa = (uint32_t)buf * 16384u, ow = (uint32_t)buf * 8192u;
    bf16x8 a00 = dsr128(aAd[0][0] + oa);
    bf16x8 a01 = dsr128(aAd[0][1] + oa);
    bf16x8 a10 = dsr128(aAd[1][0] + oa);
    bf16x8 a11 = dsr128(aAd[1][1] + oa);
    bf16x8 b0  = dsr128(wAd[0] + ow);
    bf16x8 b1  = dsr128(wAd[1] + ow);
    bf16x8 c00 = dsr128(aAd[0][0] + oa + 8192);
    bf16x8 c01 = dsr128(aAd[0][1] + oa + 8192);
    bf16x8 c10 = dsr128(aAd[1][0] + oa + 8192);
    bf16x8 c11 = dsr128(aAd[1][1] + oa + 8192);
    bf16x8 d0  = dsr128(wAd[0] + ow + 4096);
    bf16x8 d1  = dsr128(wAd[1] + ow + 4096);
    asm volatile("s_waitcnt lgkmcnt(0)" ::: "memory");
    __builtin_amdgcn_sched_barrier(0);
    __builtin_amdgcn_s_setprio(1);
    acc[0] = __builtin_amdgcn_mfma_f32_16x16x32_bf16(a00, b0, acc[0], 0, 0, 0);
    acc[1] = __builtin_amdgcn_mfma_f32_16x16x32_bf16(a10, b0, acc[1], 0, 0, 0);
    acc[0] = __builtin_amdgcn_mfma_f32_16x16x32_bf16(a01, b1, acc[0], 0, 0, 0);
    acc[1] = __builtin_amdgcn_mfma_f32_16x16x32_bf16(a11, b1, acc[1], 0, 0, 0);
    acc[0] = __builtin_amdgcn_mfma_f32_16x16x32_bf16(c00, d0, acc[0], 0, 0, 0);
    acc[1] = __builtin_amdgcn_mfma_f32_16x16x32_bf16(c10, d0, acc[1], 0, 0, 0);
    acc[0] = __builtin_amdgcn_mfma_f32_16x16x32_bf16(c01, d1, acc[0], 0, 0, 0);
    acc[1] = __builtin_amdgcn_mfma_f32_16x16x32_bf16(c11, d1, acc[1], 0, 0, 0);
    __builtin_amdgcn_s_setprio(0);
  };

  stage(0); stage(1);
  int cur = 0, nx = 2;
  for (int i = 0; i < nIter - 2; ++i) {
    asm volatile("s_waitcnt vmcnt(6)" ::: "memory");
    __builtin_amdgcn_s_barrier();
    stage(nx);
    compute(cur);
    cur = (cur == 2) ? 0 : cur + 1;
    nx  = (nx == 2) ? 0 : nx + 1;
  }
  asm volatile("s_waitcnt vmcnt(6)" ::: "memory");
  __builtin_amdgcn_s_barrier();
  compute(cur);
  cur = (cur == 2) ? 0 : cur + 1;
  asm volatile("s_waitcnt vmcnt(0)" ::: "memory");
  __builtin_amdgcn_s_barrier();
  compute(cur);
}

// ================= phase1 (bf16, BK=128, z-balanced + XCD-paired) =================
// z = bx>>8 (48-iter z=0 blocks first, 36-iter z=1 second: one of each per CU).
// mh = idx>>7, n0 = idx&127: weight pair (n, n+128) -> same XCD -> L2 hit.

__global__ __launch_bounds__(256, 2) void phase1_v14(Ctx c, float edsc) {
  __shared__ __align__(16) __bf16 lsA[3][8192];   // 48KB
  __shared__ __align__(16) __bf16 lsW[3][4096];   // 24KB
  int t = threadIdx.x, w = t >> 6, l = t & 63;
  int l16 = l & 15, lg = l >> 4, wm = w >> 1, wn = w & 1;
  int bx = blockIdx.x;
  int z = bx >> 8, idx = bx & 255;
  int mh = idx >> 7, n0 = (idx & 127) * 32;
  f32x4 acc[2];
  f32x4 z4 = {0.f, 0.f, 0.f, 0.f};
  acc[0] = z4; acc[1] = z4;

  Seg segs[2]; int nIter, N;
  float *v, *j, *rf, *tr; const float* aux; const __bf16* buf; uchar* sf8;
  if (z == 0) {
    segs[0] = { c.ed2_bf + (size_t)mh * 64 * D2, (unsigned)D2, c.V1t + (size_t)n0 * D2, (unsigned)D2, 32 };
    segs[1] = { c.eg0_bf + (size_t)mh * 64 * D0, (unsigned)D0, c.W0t + (size_t)n0 * D0, (unsigned)D0, 16 };
    nIter = 48; N = D1;
    v = c.v1; j = c.j1; rf = c.r1; tr = c.tr1; buf = c.eg1_bf; aux = c.xV0T; sf8 = c.s1_f8;
  } else {
    segs[0] = { c.ed3_bf + (size_t)mh * 64 * D3, (unsigned)D3, c.V2t + (size_t)n0 * D3, (unsigned)D3, 4 };
    segs[1] = { c.eg1_bf + (size_t)mh * 64 * D1, (unsigned)D1, c.W1t + (size_t)n0 * D1, (unsigned)D1, 32 };
    nIter = 36; N = D2;
    v = c.v2; j = c.j2; rf = c.r2; tr = c.tr2; buf = c.ed2_bf; aux = c.yW2T; sf8 = c.s2_f8;
  }

  run_gemm128(segs, nIter, &lsA[0][0], &lsW[0][0], t, wm, wn, l16, lg, acc);

  int n = n0 + wn * 16 + l16;
#pragma unroll
  for (int mt = 0; mt < 2; ++mt) {
#pragma unroll
    for (int r = 0; r < 4; ++r) {
      int b = mh * 64 + wm * 32 + mt * 16 + lg * 4 + r;
      size_t idx2 = (size_t)b * N + n;
      float to = tr[idx2];
      float ti = acc[mt][r] - (float)buf[idx2] - edsc * (to - aux[idx2]);
      float jo = j[idx2];
      float jn = jo + 0.1f * (ti - jo);
      float ro = rf[idx2];
      float vo = v[idx2];
      bool refr = ro > 0.0f;
      float vn = refr ? vo : (vo + 0.05f * (jn - vo));
      float sp = (!refr && vn > 1.0f) ? 1.0f : 0.0f;
      if (sp != 0.0f) vn = 0.0f;
      float rn = fmaxf(ro - 1.0f, 0.0f);
      if (sp != 0.0f) rn = 2.0f;
      float tn = to - 0.05f * to + sp;
      v[idx2] = vn; j[idx2] = jn; rf[idx2] = rn; tr[idx2] = tn;
      sf8[idx2] = (sp != 0.0f) ? (uchar)0x38 : (uchar)0;  // fp8 e4m3: 1.0 / 0.0 exact
    }
  }
}

// ================= phase2 (fp8 engine, BK=128 — v13, proven) =================

__global__ __launch_bounds__(256, 2) void phase2_v13(Ctx c) {
  __shared__ __align__(16) uchar lsA[4][8192];
  __shared__ __align__(16) uchar lsW[4][8192];
  int t = threadIdx.x, w = t >> 6, l = t & 63;
  int l16 = l & 15, lg = l >> 4, wm = w >> 1, wn = w & 1;
  int g = blockIdx.x, mh = blockIdx.y;

  const uchar *A, *W; int n0; bool isA;
  if (g < 96) { isA = true;  A = c.s1_f8 + (size_t)mh * 64 * D1; W = c.WA8 + (size_t)g * 64 * 4096;        n0 = g * 64; }
  else        { isA = false; A = c.s2_f8 + (size_t)mh * 64 * D2; W = c.WB8 + (size_t)(g - 96) * 64 * 4096; n0 = (g - 96) * 64; }

  f32x4 acc[4];
  f32x4 z4 = {0.f, 0.f, 0.f, 0.f};
#pragma unroll
  for (int i = 0; i < 4; i++) acc[i] = z4;

  int row = t >> 2, u = t & 3;
  int su = (u ^ ((row >> 1) & 3)) * 16;
  const uchar* pA = A + (size_t)row * 4096 + su;   // half0; half1 at +64
  const uchar* pW = W + (size_t)row * 4096 + su;
  uchar* dA = &lsA[0][0] + t * 16;                 // half0; half1 at +4096
  uchar* dW = &lsW[0][0] + t * 16;
  auto stage = [&](int s) {
    uint32_t o = (uint32_t)(s & 3) * 8192u;
    gload16(pA,      dA + o);
    gload16(pA + 64, dA + o + 4096);
    gload16(pW,      dW + o);
    gload16(pW + 64, dW + o + 4096);
    pA += 128; pW += 128;
  };

  uint32_t aB = lds_off(lsA), wB = lds_off(lsW);
  uint32_t adA[2][2], adW[2][2];
#pragma unroll
  for (int mt = 0; mt < 2; ++mt)
#pragma unroll
    for (int ks = 0; ks < 2; ++ks) {
      int ra = wm * 32 + mt * 16 + l16;
      adA[mt][ks] = aB + (uint32_t)ra * 64u
                  + (uint32_t)((((ks * 2 + (lg >> 1)) ^ ((ra >> 1) & 3)) * 16) + (lg & 1) * 8);
    }
#pragma unroll
  for (int nt = 0; nt < 2; ++nt)
#pragma unroll
    for (int ks = 0; ks < 2; ++ks) {
      int rw = wn * 32 + nt * 16 + l16;
      adW[nt][ks] = wB + (uint32_t)rw * 64u
                  + (uint32_t)((((ks * 2 + (lg >> 1)) ^ ((rw >> 1) & 3)) * 16) + (lg & 1) * 8);
    }

  auto compute = [&](int i) {
    uint32_t off = (uint32_t)(i & 3) * 8192u;
    long a0h0  = dsr64(adA[0][0] + off);
    long a1h0  = dsr64(adA[1][0] + off);
    long b0h0  = dsr64(adW[0][0] + off);
    long b1h0  = dsr64(adW[1][0] + off);
    long a0h0b = dsr64(adA[0][1] + off);
    long a1h0b = dsr64(adA[1][1] + off);
    long b0h0b = dsr64(adW[0][1] + off);
    long b1h0b = dsr64(adW[1][1] + off);
    long a0h1  = dsr64(adA[0][0] + off + 4096);
    long a1h1  = dsr64(adA[1][0] + off + 4096);
    long b0h1  = dsr64(adW[0][0] + off + 4096);
    long b1h1  = dsr64(adW[1][0] + off + 4096);
    long a0h1b = dsr64(adA[0][1] + off + 4096);
    long a1h1b = dsr64(adA[1][1] + off + 4096);
    long b0h1b = dsr64(adW[0][1] + off + 4096);
    long b1h1b = dsr64(adW[1][1] + off + 4096);
    asm volatile("s_waitcnt lgkmcnt(0)" ::: "memory");
    __builtin_amdgcn_sched_barrier(0);
    __builtin_amdgcn_s_setprio(1);
    acc[0] = __builtin_amdgcn_mfma_f32_16x16x32_fp8_fp8(a0h0,  b0h0,  acc[0], 0, 0, 0);
    acc[1] = __builtin_amdgcn_mfma_f32_16x16x32_fp8_fp8(a0h0,  b1h0,  acc[1], 0, 0, 0);
    acc[2] = __builtin_amdgcn_mfma_f32_16x16x32_fp8_fp8(a1h0,  b0h0,  acc[2], 0, 0, 0);
    acc[3] = __builtin_amdgcn_mfma_f32_16x16x32_fp8_fp8(a1h0,  b1h0,  acc[3], 0, 0, 0);
    acc[0] = __builtin_amdgcn_mfma_f32_16x16x32_fp8_fp8(a0h0b, b0h0b, acc[0], 0, 0, 0);
    acc[1] = __builtin_amdgcn_mfma_f32_16x16x32_fp8_fp8(a0h0b, b1h0b, acc[1], 0, 0, 0);
    acc[2] = __builtin_amdgcn_mfma_f32_16x16x32_fp8_fp8(a1h0b, b0h0b, acc[2], 0, 0, 0);
    acc[3] = __builtin_amdgcn_mfma_f32_16x16x32_fp8_fp8(a1h0b, b1h0b, acc[3], 0, 0, 0);
    acc[0] = __builtin_amdgcn_mfma_f32_16x16x32_fp8_fp8(a0h1,  b0h1,  acc[0], 0, 0, 0);
    acc[1] = __builtin_amdgcn_mfma_f32_16x16x32_fp8_fp8(a0h1,  b1h1,  acc[1], 0, 0, 0);
    acc[2] = __builtin_amdgcn_mfma_f32_16x16x32_fp8_fp8(a1h1,  b0h1,  acc[2], 0, 0, 0);
    acc[3] = __builtin_amdgcn_mfma_f32_16x16x32_fp8_fp8(a1h1,  b1h1,  acc[3], 0, 0, 0);
    acc[0] = __builtin_amdgcn_mfma_f32_16x16x32_fp8_fp8(a0h1b, b0h1b, acc[0], 0, 0, 0);
    acc[1] = __builtin_amdgcn_mfma_f32_16x16x32_fp8_fp8(a0h1b, b1h1b, acc[1], 0, 0, 0);
    acc[2] = __builtin_amdgcn_mfma_f32_16x16x32_fp8_fp8(a1h1b, b0h1b, acc[2], 0, 0, 0);
    acc[3] = __builtin_amdgcn_mfma_f32_16x16x32_fp8_fp8(a1h1b, b1h1b, acc[3], 0, 0, 0);
    __builtin_amdgcn_s_setprio(0);
  };

  const int nIter = 32;
  stage(0); stage(1); stage(2);
  for (int i = 0; i < nIter - 3; ++i) {
    asm volatile("s_waitcnt vmcnt(8)" ::: "memory");
    __builtin_amdgcn_s_barrier();
    stage(i + 3);
    compute(i);
  }
  asm volatile("s_waitcnt vmcnt(8)" ::: "memory");
  __builtin_amdgcn_s_barrier();
  compute(nIter - 3);
  asm volatile("s_waitcnt vmcnt(4)" ::: "memory");
  __builtin_amdgcn_s_barrier();
  compute(nIter - 2);
  asm volatile("s_waitcnt vmcnt(0)" ::: "memory");
  __builtin_amdgcn_s_barrier();
  compute(nIter - 1);

#pragma unroll
  for (int mt = 0; mt < 2; ++mt)
#pragma unroll
    for (int nt = 0; nt < 2; ++nt) {
      int nn = n0 + wn * 32 + nt * 16 + l16;
#pragma unroll
      for (int r = 0; r < 4; ++r) {
        int b = mh * 64 + wm * 32 + mt * 16 + lg * 4 + r;
        float av = acc[mt * 2 + nt][r];
        if (isA) {
          if (nn < 2048) {            // mode 0: eg0 (+ zd update)
            size_t idx = (size_t)b * D0 + nn;
            float zo = c.zd[idx]; float zn = zo - 0.1f * zo + c.x[idx];
            c.zd[idx] = zn;
            c.eg0_bf[idx] = (__bf16)(0.5f * (zn - av));
          } else {                    // mode 2: ed2
            size_t idx = (size_t)b * D2 + (nn - 2048);
            c.ed2_bf[idx] = (__bf16)(0.5f * (c.tr2[idx] - av));
          }
        } else {
          if (nn < 4096) {            // mode 1: eg1
            size_t idx = (size_t)b * D1 + nn;
            c.eg1_bf[idx] = (__bf16)(0.5f * (c.tr1[idx] - av));
          } else {                    // mode 3: ed3 (+ zl update, output)
            size_t idx = (size_t)b * D3 + (nn - 4096);
            float zo = c.zl[idx]; float zn = zo - 0.1f * zo + c.y[idx];
            c.zl[idx] = zn;
            float e = 0.5f * (zn - av);
            c.out[idx] = e; c.ed3_bf[idx] = (__bf16)e;
          }
        }
      }
    }
}

// ================= precomp (bf16 DMA engine, runs once) =================

__global__ __launch_bounds__(256, 2) void precomp_v6(Ctx c) {
  __shared__ __align__(16) __bf16 lsA[4][4096];
  __shared__ __align__(16) __bf16 lsW[4][2048];
  int t = threadIdx.x, w = t >> 6, l = t & 63;
  int l16 = l & 15, lg = l >> 4, wm = w >> 1, wn = w & 1;
  int n0 = blockIdx.x * 32, mh = blockIdx.y;
  f32x4 acc[2];
  f32x4 z4 = {0.f, 0.f, 0.f, 0.f};
  acc[0] = z4; acc[1] = z4;

  Seg segs[2]; int nIter, N; float* outp;
  if (blockIdx.z == 0) {
    segs[0] = { c.x_bf + (size_t)mh * 64 * D0, (unsigned)D0, c.V0n + (size_t)n0 * D0, (unsigned)D0, 32 };
    nIter = 32; N = D1; outp = c.xV0T;
  } else {
    segs[0] = { c.y_bf + (size_t)mh * 64 * D3, (unsigned)D3, c.W2n + (size_t)n0 * D3, (unsigned)D3, 8 };
    nIter = 8; N = D2; outp = c.yW2T;
  }
  segs[1] = segs[0];

  run_gemm(segs, nIter, &lsA[0][0], &lsW[0][0], t, wm, wn, l16, lg, acc);

  int n = n0 + wn * 16 + l16;
#pragma unroll
  for (int mt = 0; mt < 2; ++mt)
#pragma unroll
    for (int r = 0; r < 4; ++r) {
      int b = mh * 64 + wm * 32 + mt * 16 + lg * 4 + r;
      outp[(size_t)b * N + n] = acc[mt][r];
    }
}

// ================= one-shot prep (split into 4 launches via g0) =================

__global__ __launch_bounds__(256) void wprep_kernel(Ctx c, int g0) {
  __shared__ float ls[64][65];
  int g = blockIdx.x + g0;
  const float* src; __bf16* tp = nullptr; uchar* n8 = nullptr; __bf16* nb = nullptr; int R, C;
  if (g < 2048)       { src = c.W0; n8 = c.WA8;                         tp = c.W0t; R = D0; C = D1; }
  else if (g < 6144)  { g -= 2048;  src = c.W1; n8 = c.WB8;             tp = c.W1t; R = D1; C = D2; }
  else if (g < 10240) { g -= 6144;  src = c.V1; n8 = c.WA8 + (size_t)2048 * 4096; tp = c.V1t; R = D2; C = D1; }
  else if (g < 10752) { g -= 10240; src = c.V2; n8 = c.WB8 + (size_t)4096 * 4096; tp = c.V2t; R = D3; C = D2; }
  else if (g < 12800) { g -= 10752; src = c.V0; nb = c.V0n; R = D1; C = D0; }
  else                { g -= 12800; src = c.W2; nb = c.W2n; R = D2; C = D3; }
  int tpr = C / 64;
  int r0 = (g / tpr) * 64, c0 = (g % tpr) * 64;
  int t = threadIdx.x, r = t >> 2, q = t & 3;

  const float4* s4 = reinterpret_cast<const float4*>(src + (size_t)(r0 + r) * C + c0 + q * 16);
  if (n8) {
    int pk[4];
#pragma unroll
    for (int i = 0; i < 4; i++) {
      float4 v = s4[i];
      ls[r][q * 16 + i * 4 + 0] = v.x; ls[r][q * 16 + i * 4 + 1] = v.y;
      ls[r][q * 16 + i * 4 + 2] = v.z; ls[r][q * 16 + i * 4 + 3] = v.w;
      int wd = __builtin_amdgcn_cvt_pk_fp8_f32(v.x, v.y, 0, false);
      wd = __builtin_amdgcn_cvt_pk_fp8_f32(v.z, v.w, wd, true);
      pk[i] = wd;
    }
    int4 pv; pv.x = pk[0]; pv.y = pk[1]; pv.z = pk[2]; pv.w = pk[3];
    *reinterpret_cast<int4*>(n8 + (size_t)(r0 + r) * C + c0 + q * 16) = pv;
    __syncthreads();
    union { __bf16 h[16]; int4 qq[2]; } wv;
#pragma unroll
    for (int i = 0; i < 16; i++) wv.h[i] = (__bf16)ls[q * 16 + i][r];
    int4* dt = reinterpret_cast<int4*>(tp + (size_t)(c0 + r) * R + r0 + q * 16);
    dt[0] = wv.qq[0]; dt[1] = wv.qq[1];
  } else {
    union { __bf16 h[16]; int4 qq[2]; } uu;
#pragma unroll
    for (int i = 0; i < 4; i++) {
      float4 v = s4[i];
      uu.h[i * 4 + 0] = (__bf16)v.x; uu.h[i * 4 + 1] = (__bf16)v.y;
      uu.h[i * 4 + 2] = (__bf16)v.z; uu.h[i * 4 + 3] = (__bf16)v.w;
    }
    int4* dn = reinterpret_cast<int4*>(nb + (size_t)(r0 + r) * C + c0 + q * 16);
    dn[0] = uu.qq[0]; dn[1] = uu.qq[1];
  }
}

// cast x,y -> bf16 AND step-0 "phase2" (s=tr=0): zd=x, zl=y, eg0=.5x, ed3=.5y.
__global__ __launch_bounds__(256) void castinit_kernel(Ctx c) {
  int i = blockIdx.x * 256 + threadIdx.x;
  const int NX = BB * D0 / 4;
  union { __bf16 h[4]; uint2 u; } p, q;
  if (i < NX) {
    float4 xv = reinterpret_cast<const float4*>(c.x)[i];
    reinterpret_cast<float4*>(c.zd)[i] = xv;
    p.h[0] = (__bf16)xv.x; p.h[1] = (__bf16)xv.y; p.h[2] = (__bf16)xv.z; p.h[3] = (__bf16)xv.w;
    reinterpret_cast<uint2*>(c.x_bf)[i] = p.u;
    q.h[0] = (__bf16)(0.5f * xv.x); q.h[1] = (__bf16)(0.5f * xv.y);
    q.h[2] = (__bf16)(0.5f * xv.z); q.h[3] = (__bf16)(0.5f * xv.w);
    reinterpret_cast<uint2*>(c.eg0_bf)[i] = q.u;
  } else {
    int k = i - NX;
    float4 yv = reinterpret_cast<const float4*>(c.y)[k];
    reinterpret_cast<float4*>(c.zl)[k] = yv;
    p.h[0] = (__bf16)yv.x; p.h[1] = (__bf16)yv.y; p.h[2] = (__bf16)yv.z; p.h[3] = (__bf16)yv.w;
    reinterpret_cast<uint2*>(c.y_bf)[k] = p.u;
    q.h[0] = (__bf16)(0.5f * yv.x); q.h[1] = (__bf16)(0.5f * yv.y);
    q.h[2] = (__bf16)(0.5f * yv.z); q.h[3] = (__bf16)(0.5f * yv.w);
    reinterpret_cast<uint2*>(c.ed3_bf)[k] = q.u;
  }
}

// ================= host =================

extern "C" void kernel_launch(void* const* d_in, const int* in_sizes, int n_in,
                              void* d_out, int out_size, void* d_ws, size_t ws_size,
                              hipStream_t stream) {
  Ctx c;
  c.x  = (const float*)d_in[0];
  c.y  = (const float*)d_in[1];
  c.W0 = (const float*)d_in[2];
  c.W1 = (const float*)d_in[3];
  c.W2 = (const float*)d_in[4];
  c.V0 = (const float*)d_in[5];
  c.V1 = (const float*)d_in[6];
  c.V2 = (const float*)d_in[7];
  c.out = (float*)d_out;

  char* p = (char*)d_ws;
  auto af = [&](size_t n) -> float* { float* r = (float*)p; p += ((n * 4 + 255) & ~(size_t)255); return r; };
  auto ah = [&](size_t n) -> __bf16* { __bf16* r = (__bf16*)p; p += ((n * 2 + 255) & ~(size_t)255); return r; };
  auto au = [&](size_t n) -> uchar* { uchar* r = (uchar*)p; p += ((n + 255) & ~(size_t)255); return r; };

  const size_t S1 = (size_t)BB * D1;
  // --- zero-initialized state (memset span) ---
  c.v1 = af(S1); c.j1 = af(S1); c.r1 = af(S1); c.tr1 = af(S1);
  c.v2 = af(S1); c.j2 = af(S1); c.r2 = af(S1); c.tr2 = af(S1);
  c.eg1_bf = ah(S1); c.ed2_bf = ah(S1);
  size_t zero_bytes = (size_t)(p - (char*)d_ws);
  // --- written-before-read buffers ---
  c.zd = af((size_t)BB * D0); c.zl = af((size_t)BB * D3);
  c.xV0T = af(S1); c.yW2T = af(S1);
  c.x_bf = ah((size_t)BB * D0); c.y_bf = ah((size_t)BB * D3);
  c.eg0_bf = ah((size_t)BB * D0); c.ed3_bf = ah((size_t)BB * D3);
  c.s1_f8 = au(S1); c.s2_f8 = au(S1);
  // --- weight copies ---
  c.W0t = ah((size_t)D0 * D1); c.W1t = ah((size_t)D1 * D2); c.V1t = ah((size_t)D2 * D1); c.V2t = ah((size_t)D3 * D2);
  c.V0n = ah((size_t)D1 * D0); c.W2n = ah((size_t)D2 * D3);
  c.WA8 = au((size_t)(D0 + D2) * 4096);   // [W0; V1] rows, K=4096
  c.WB8 = au((size_t)(D1 + D3) * 4096);   // [W1; V2] rows, K=4096

  hipMemsetAsync(d_ws, 0, zero_bytes, stream);
  castinit_kernel<<<320, 256, 0, stream>>>(c);
  // order: phase1-step1 inputs (V1t, W0t) written LAST -> L3-resident at step 1
  wprep_kernel<<<3072, 256, 0, stream>>>(c, 10240);   // V2 + V0 + W2
  wprep_kernel<<<4096, 256, 0, stream>>>(c, 2048);    // W1
  wprep_kernel<<<4096, 256, 0, stream>>>(c, 6144);    // V1
  wprep_kernel<<<2048, 256, 0, stream>>>(c, 0);       // W0
  precomp_v6<<<dim3(128, 2, 2), 256, 0, stream>>>(c);

  for (int s = 1; s < NSTEPS; s++) {
    phase1_v14<<<512, 256, 0, stream>>>(c, 0.5f);
    phase2_v13<<<dim3(168, 2), 256, 0, stream>>>(c);
  }
}

// Round 9
// 840.383 us; speedup vs baseline: 1.1789x; 1.0245x over previous
//
#include <hip/hip_runtime.h>

// bPC SNN forward, 16 steps, B=128, dims 2048/4096/4096/512.
// v15: phase2 staging rewritten to 128B global segments per row (8 lanes x 16B,
// XOR-8 swizzle, LDS rows at 128B stride). v13/v14 rate accounting: phase1
// (128B segments) achieves ~40 B/cyc/CU LDS-DMA ingress; phase2 (64B segments)
// only ~17 — half-line L2 requests. Same tile/pipeline/MFMA order -> bit-
// identical numerics. Cost: ~4-way LDS read conflicts (cheap). phase1 = v14
// (control). If neutral, next theory is L3 W-traffic (M=128/N=32).

#define DEVINL __device__ __forceinline__

using bf16x8 = __attribute__((ext_vector_type(8))) __bf16;
using f32x4  = __attribute__((ext_vector_type(4))) float;
using i32x4  = __attribute__((ext_vector_type(4))) int;
typedef unsigned char uchar;

static constexpr int BB = 128;
static constexpr int D0 = 2048, D1 = 4096, D2 = 4096, D3 = 512;
static constexpr int NSTEPS = 16;

struct Ctx {
  const float *x, *y, *W0, *W1, *W2, *V0, *V1, *V2;
  float *v1, *j1, *r1, *tr1, *v2, *j2, *r2, *tr2;
  float *zd, *zl, *xV0T, *yW2T;
  __bf16 *x_bf, *y_bf, *eg0_bf, *eg1_bf, *ed2_bf, *ed3_bf;
  uchar *s1_f8, *s2_f8, *WA8, *WB8;      // fp8 spikes + stacked fp8 weights
  __bf16 *W0t, *W1t, *V1t, *V2t, *V0n, *W2n;
  float *out;
};

DEVINL void gload16(const void* g, void* l) {
  __builtin_amdgcn_global_load_lds(
      (const __attribute__((address_space(1))) void*)g,
      (__attribute__((address_space(3))) void*)l, 16, 0, 0);
}
DEVINL uint32_t lds_off(const void* p) {
  return (uint32_t)(uintptr_t)(__attribute__((address_space(3))) const void*)p;
}
DEVINL bf16x8 dsr128(uint32_t addr) {
  i32x4 r;
  asm volatile("ds_read_b128 %0, %1" : "=v"(r) : "v"(addr));
  return __builtin_bit_cast(bf16x8, r);
}
DEVINL long dsr64(uint32_t addr) {
  long r;
  asm volatile("ds_read_b64 %0, %1" : "=v"(r) : "v"(addr));
  return r;
}

// ================= bf16 engines =================
struct Seg { const __bf16* A; unsigned ldA; const __bf16* W; unsigned ldW; int iters; };
struct SPtr { const __bf16 *a0, *a1, *w; };

DEVINL SPtr mkptr(const Seg& s, int t) {
  int r = t >> 3;
  int u = ((t & 7) ^ (r & 7)) * 8;
  SPtr p;
  p.a0 = s.A + (size_t)r * s.ldA + u;
  p.a1 = s.A + (size_t)(r + 32) * s.ldA + u;
  p.w  = s.W + (size_t)r * s.ldW + u;
  return p;
}

// ---- BK=64 engine (precomp) ----
DEVINL void run_gemm(const Seg* segs, int nIter, __bf16* lsA, __bf16* lsW,
                     int t, int wm, int wn, int l16, int lg, f32x4* acc) {
  const int seg0it = segs[0].iters;
  SPtr p = mkptr(segs[0], t);
  int nxt = 0;
  auto stage = [&](int s) {
    __bf16* bA = lsA + (s & 3) * 4096;
    __bf16* bW = lsW + (s & 3) * 2048;
    gload16(p.a0, bA + t * 8);
    gload16(p.a1, bA + 2048 + t * 8);
    gload16(p.w,  bW + t * 8);
    p.a0 += 64; p.a1 += 64; p.w += 64;
    if (++nxt == seg0it) p = mkptr(segs[1], t);
  };

  const int x7 = l16 & 7;
  uint32_t aB = lds_off(lsA), wB = lds_off(lsW);
  uint32_t aAd[2][2], wAd[2];
#pragma unroll
  for (int mt = 0; mt < 2; ++mt)
#pragma unroll
    for (int ks = 0; ks < 2; ++ks)
      aAd[mt][ks] = aB + (uint32_t)(wm * 32 + mt * 16 + l16) * 128u
                       + (uint32_t)(((ks * 4 + lg) ^ x7) * 16);
#pragma unroll
  for (int ks = 0; ks < 2; ++ks)
    wAd[ks] = wB + (uint32_t)(wn * 16 + l16) * 128u
                 + (uint32_t)(((ks * 4 + lg) ^ x7) * 16);

  auto compute = [&](int i) {
    uint32_t oa = (uint32_t)(i & 3) * 8192u, ow = (uint32_t)(i & 3) * 4096u;
    bf16x8 a00 = dsr128(aAd[0][0] + oa);
    bf16x8 a01 = dsr128(aAd[0][1] + oa);
    bf16x8 a10 = dsr128(aAd[1][0] + oa);
    bf16x8 a11 = dsr128(aAd[1][1] + oa);
    bf16x8 b0  = dsr128(wAd[0] + ow);
    bf16x8 b1  = dsr128(wAd[1] + ow);
    asm volatile("s_waitcnt lgkmcnt(0)" ::: "memory");
    __builtin_amdgcn_sched_barrier(0);
    __builtin_amdgcn_s_setprio(1);
    acc[0] = __builtin_amdgcn_mfma_f32_16x16x32_bf16(a00, b0, acc[0], 0, 0, 0);
    acc[1] = __builtin_amdgcn_mfma_f32_16x16x32_bf16(a10, b0, acc[1], 0, 0, 0);
    acc[0] = __builtin_amdgcn_mfma_f32_16x16x32_bf16(a01, b1, acc[0], 0, 0, 0);
    acc[1] = __builtin_amdgcn_mfma_f32_16x16x32_bf16(a11, b1, acc[1], 0, 0, 0);
    __builtin_amdgcn_s_setprio(0);
  };

  stage(0); stage(1); stage(2);
  for (int i = 0; i < nIter - 3; ++i) {
    asm volatile("s_waitcnt vmcnt(6)" ::: "memory");
    __builtin_amdgcn_s_barrier();
    stage(i + 3);
    compute(i);
  }
  asm volatile("s_waitcnt vmcnt(6)" ::: "memory");
  __builtin_amdgcn_s_barrier();
  compute(nIter - 3);
  asm volatile("s_waitcnt vmcnt(3)" ::: "memory");
  __builtin_amdgcn_s_barrier();
  compute(nIter - 2);
  asm volatile("s_waitcnt vmcnt(0)" ::: "memory");
  __builtin_amdgcn_s_barrier();
  compute(nIter - 1);
}

// ---- BK=128 engine (phase1 v14): 3 buffers (A 16KB + W 8KB each), 2 ahead.
DEVINL void run_gemm128(const Seg* segs, int nIter, __bf16* lsA, __bf16* lsW,
                        int t, int wm, int wn, int l16, int lg, f32x4* acc) {
  const int seg0it = segs[0].iters;   // in BK=128 units
  SPtr p = mkptr(segs[0], t);
  int nxt = 0;
  auto stage = [&](int buf) {
    __bf16* bA = lsA + buf * 8192;
    __bf16* bW = lsW + buf * 4096;
    gload16(p.a0,      bA + t * 8);          // K half0, rows 0..31
    gload16(p.a1,      bA + 2048 + t * 8);   // K half0, rows 32..63
    gload16(p.a0 + 64, bA + 4096 + t * 8);   // K half1, rows 0..31
    gload16(p.a1 + 64, bA + 6144 + t * 8);   // K half1, rows 32..63
    gload16(p.w,       bW + t * 8);          // W half0
    gload16(p.w + 64,  bW + 2048 + t * 8);   // W half1
    p.a0 += 128; p.a1 += 128; p.w += 128;
    if (++nxt == seg0it) p = mkptr(segs[1], t);
  };

  const int x7 = l16 & 7;
  uint32_t aB = lds_off(lsA), wB = lds_off(lsW);
  uint32_t aAd[2][2], wAd[2];
#pragma unroll
  for (int mt = 0; mt < 2; ++mt)
#pragma unroll
    for (int ks = 0; ks < 2; ++ks)
      aAd[mt][ks] = aB + (uint32_t)(wm * 32 + mt * 16 + l16) * 128u
                       + (uint32_t)(((ks * 4 + lg) ^ x7) * 16);
#pragma unroll
  for (int ks = 0; ks < 2; ++ks)
    wAd[ks] = wB + (uint32_t)(wn * 16 + l16) * 128u
                 + (uint32_t)(((ks * 4 + lg) ^ x7) * 16);

  auto compute = [&](int buf) {
    uint32_t oa = (uint32_t)buf * 16384u, ow = (uint32_t)buf * 8192u;
    bf16x8 a00 = dsr128(aAd[0][0] + oa);
    bf16x8 a01 = dsr128(aAd[0][1] + oa);
    bf16x8 a10 = dsr128(aAd[1][0] + oa);
    bf16x8 a11 = dsr128(aAd[1][1] + oa);
    bf16x8 b0  = dsr128(wAd[0] + ow);
    bf16x8 b1  = dsr128(wAd[1] + ow);
    bf16x8 c00 = dsr128(aAd[0][0] + oa + 8192);
    bf16x8 c01 = dsr128(aAd[0][1] + oa + 8192);
    bf16x8 c10 = dsr128(aAd[1][0] + oa + 8192);
    bf16x8 c11 = dsr128(aAd[1][1] + oa + 8192);
    bf16x8 d0  = dsr128(wAd[0] + ow + 4096);
    bf16x8 d1  = dsr128(wAd[1] + ow + 4096);
    asm volatile("s_waitcnt lgkmcnt(0)" ::: "memory");
    __builtin_amdgcn_sched_barrier(0);
    __builtin_amdgcn_s_setprio(1);
    acc[0] = __builtin_amdgcn_mfma_f32_16x16x32_bf16(a00, b0, acc[0], 0, 0, 0);
    acc[1] = __builtin_amdgcn_mfma_f32_16x16x32_bf16(a10, b0, acc[1], 0, 0, 0);
    acc[0] = __builtin_amdgcn_mfma_f32_16x16x32_bf16(a01, b1, acc[0], 0, 0, 0);
    acc[1] = __builtin_amdgcn_mfma_f32_16x16x32_bf16(a11, b1, acc[1], 0, 0, 0);
    acc[0] = __builtin_amdgcn_mfma_f32_16x16x32_bf16(c00, d0, acc[0], 0, 0, 0);
    acc[1] = __builtin_amdgcn_mfma_f32_16x16x32_bf16(c10, d0, acc[1], 0, 0, 0);
    acc[0] = __builtin_amdgcn_mfma_f32_16x16x32_bf16(c01, d1, acc[0], 0, 0, 0);
    acc[1] = __builtin_amdgcn_mfma_f32_16x16x32_bf16(c11, d1, acc[1], 0, 0, 0);
    __builtin_amdgcn_s_setprio(0);
  };

  stage(0); stage(1);
  int cur = 0, nx = 2;
  for (int i = 0; i < nIter - 2; ++i) {
    asm volatile("s_waitcnt vmcnt(6)" ::: "memory");
    __builtin_amdgcn_s_barrier();
    stage(nx);
    compute(cur);
    cur = (cur == 2) ? 0 : cur + 1;
    nx  = (nx == 2) ? 0 : nx + 1;
  }
  asm volatile("s_waitcnt vmcnt(6)" ::: "memory");
  __builtin_amdgcn_s_barrier();
  compute(cur);
  cur = (cur == 2) ? 0 : cur + 1;
  asm volatile("s_waitcnt vmcnt(0)" ::: "memory");
  __builtin_amdgcn_s_barrier();
  compute(cur);
}

// ================= phase1 (bf16, BK=128, z-balanced + XCD-paired — v14) =================

__global__ __launch_bounds__(256, 2) void phase1_v14(Ctx c, float edsc) {
  __shared__ __align__(16) __bf16 lsA[3][8192];   // 48KB
  __shared__ __align__(16) __bf16 lsW[3][4096];   // 24KB
  int t = threadIdx.x, w = t >> 6, l = t & 63;
  int l16 = l & 15, lg = l >> 4, wm = w >> 1, wn = w & 1;
  int bx = blockIdx.x;
  int z = bx >> 8, idx = bx & 255;
  int mh = idx >> 7, n0 = (idx & 127) * 32;
  f32x4 acc[2];
  f32x4 z4 = {0.f, 0.f, 0.f, 0.f};
  acc[0] = z4; acc[1] = z4;

  Seg segs[2]; int nIter, N;
  float *v, *j, *rf, *tr; const float* aux; const __bf16* buf; uchar* sf8;
  if (z == 0) {
    segs[0] = { c.ed2_bf + (size_t)mh * 64 * D2, (unsigned)D2, c.V1t + (size_t)n0 * D2, (unsigned)D2, 32 };
    segs[1] = { c.eg0_bf + (size_t)mh * 64 * D0, (unsigned)D0, c.W0t + (size_t)n0 * D0, (unsigned)D0, 16 };
    nIter = 48; N = D1;
    v = c.v1; j = c.j1; rf = c.r1; tr = c.tr1; buf = c.eg1_bf; aux = c.xV0T; sf8 = c.s1_f8;
  } else {
    segs[0] = { c.ed3_bf + (size_t)mh * 64 * D3, (unsigned)D3, c.V2t + (size_t)n0 * D3, (unsigned)D3, 4 };
    segs[1] = { c.eg1_bf + (size_t)mh * 64 * D1, (unsigned)D1, c.W1t + (size_t)n0 * D1, (unsigned)D1, 32 };
    nIter = 36; N = D2;
    v = c.v2; j = c.j2; rf = c.r2; tr = c.tr2; buf = c.ed2_bf; aux = c.yW2T; sf8 = c.s2_f8;
  }

  run_gemm128(segs, nIter, &lsA[0][0], &lsW[0][0], t, wm, wn, l16, lg, acc);

  int n = n0 + wn * 16 + l16;
#pragma unroll
  for (int mt = 0; mt < 2; ++mt) {
#pragma unroll
    for (int r = 0; r < 4; ++r) {
      int b = mh * 64 + wm * 32 + mt * 16 + lg * 4 + r;
      size_t idx2 = (size_t)b * N + n;
      float to = tr[idx2];
      float ti = acc[mt][r] - (float)buf[idx2] - edsc * (to - aux[idx2]);
      float jo = j[idx2];
      float jn = jo + 0.1f * (ti - jo);
      float ro = rf[idx2];
      float vo = v[idx2];
      bool refr = ro > 0.0f;
      float vn = refr ? vo : (vo + 0.05f * (jn - vo));
      float sp = (!refr && vn > 1.0f) ? 1.0f : 0.0f;
      if (sp != 0.0f) vn = 0.0f;
      float rn = fmaxf(ro - 1.0f, 0.0f);
      if (sp != 0.0f) rn = 2.0f;
      float tn = to - 0.05f * to + sp;
      v[idx2] = vn; j[idx2] = jn; rf[idx2] = rn; tr[idx2] = tn;
      sf8[idx2] = (sp != 0.0f) ? (uchar)0x38 : (uchar)0;  // fp8 e4m3: 1.0 / 0.0 exact
    }
  }
}

// ================= phase2 (fp8 engine, 128B DMA segments) =================
// Same geometry as v13 (64M x 64N, BK=128B, 32 iters, 4-buf, grid (168,2)),
// but staging reads 128B contiguous per row (8 lanes x 16B, XOR-8 swizzle):
// row = t>>3, su = ((t&7) ^ ((row>>1)&7))*16. LDS rows at 128B stride; read
// addr = base + ra*128 + ((j ^ ((ra>>1)&7))*16) + (lg&1)*8, j = h*4+ks*2+
// (lg>>1); (ks,h) variants via addr XOR 32/64/96 (requires 128B-aligned LDS).
// K-order per output unchanged -> bit-identical to v13/v14.

__global__ __launch_bounds__(256, 2) void phase2_v15(Ctx c) {
  __shared__ __align__(128) uchar lsA[4][8192];
  __shared__ __align__(128) uchar lsW[4][8192];
  int t = threadIdx.x, w = t >> 6, l = t & 63;
  int l16 = l & 15, lg = l >> 4, wm = w >> 1, wn = w & 1;
  int g = blockIdx.x, mh = blockIdx.y;

  const uchar *A, *W; int n0; bool isA;
  if (g < 96) { isA = true;  A = c.s1_f8 + (size_t)mh * 64 * D1; W = c.WA8 + (size_t)g * 64 * 4096;        n0 = g * 64; }
  else        { isA = false; A = c.s2_f8 + (size_t)mh * 64 * D2; W = c.WB8 + (size_t)(g - 96) * 64 * 4096; n0 = (g - 96) * 64; }

  f32x4 acc[4];
  f32x4 z4 = {0.f, 0.f, 0.f, 0.f};
#pragma unroll
  for (int i = 0; i < 4; i++) acc[i] = z4;

  int row8 = t >> 3, u8 = t & 7;
  int su8 = (u8 ^ ((row8 >> 1) & 7)) * 16;
  const uchar* pA0 = A + (size_t)row8 * 4096 + su8;          // rows 0..31
  const uchar* pA1 = A + (size_t)(row8 + 32) * 4096 + su8;   // rows 32..63 (same swz phase: 32/2=16==0 mod 8)
  const uchar* pW0 = W + (size_t)row8 * 4096 + su8;
  const uchar* pW1 = W + (size_t)(row8 + 32) * 4096 + su8;
  uchar* dA = &lsA[0][0] + t * 16;
  uchar* dW = &lsW[0][0] + t * 16;
  auto stage = [&](int s) {
    uint32_t o = (uint32_t)(s & 3) * 8192u;
    gload16(pA0, dA + o);            // LDS rows 0..31  (row*128 + unit*16)
    gload16(pA1, dA + o + 4096);     // LDS rows 32..63
    gload16(pW0, dW + o);
    gload16(pW1, dW + o + 4096);
    pA0 += 128; pA1 += 128; pW0 += 128; pW1 += 128;
  };

  uint32_t aB = lds_off(lsA), wB = lds_off(lsW);
  uint32_t adA[2], adW[2];
#pragma unroll
  for (int mt = 0; mt < 2; ++mt) {
    int ra = wm * 32 + mt * 16 + l16;
    adA[mt] = aB + (uint32_t)ra * 128u
            + (uint32_t)((((lg >> 1) ^ ((ra >> 1) & 7)) * 16) + (lg & 1) * 8);
  }
#pragma unroll
  for (int nt = 0; nt < 2; ++nt) {
    int rw = wn * 32 + nt * 16 + l16;
    adW[nt] = wB + (uint32_t)rw * 128u
            + (uint32_t)((((lg >> 1) ^ ((rw >> 1) & 7)) * 16) + (lg & 1) * 8);
  }

  auto compute = [&](int i) {
    uint32_t off = (uint32_t)(i & 3) * 8192u;
    uint32_t A0 = adA[0] + off, A1 = adA[1] + off;
    uint32_t B0 = adW[0] + off, B1 = adW[1] + off;
    long a0v0 = dsr64(A0);         long a1v0 = dsr64(A1);         // h0 ks0
    long b0v0 = dsr64(B0);         long b1v0 = dsr64(B1);
    long a0v1 = dsr64(A0 ^ 32u);   long a1v1 = dsr64(A1 ^ 32u);   // h0 ks1
    long b0v1 = dsr64(B0 ^ 32u);   long b1v1 = dsr64(B1 ^ 32u);
    long a0v2 = dsr64(A0 ^ 64u);   long a1v2 = dsr64(A1 ^ 64u);   // h1 ks0
    long b0v2 = dsr64(B0 ^ 64u);   long b1v2 = dsr64(B1 ^ 64u);
    long a0v3 = dsr64(A0 ^ 96u);   long a1v3 = dsr64(A1 ^ 96u);   // h1 ks1
    long b0v3 = dsr64(B0 ^ 96u);   long b1v3 = dsr64(B1 ^ 96u);
    asm volatile("s_waitcnt lgkmcnt(0)" ::: "memory");
    __builtin_amdgcn_sched_barrier(0);
    __builtin_amdgcn_s_setprio(1);
    acc[0] = __builtin_amdgcn_mfma_f32_16x16x32_fp8_fp8(a0v0, b0v0, acc[0], 0, 0, 0);
    acc[1] = __builtin_amdgcn_mfma_f32_16x16x32_fp8_fp8(a0v0, b1v0, acc[1], 0, 0, 0);
    acc[2] = __builtin_amdgcn_mfma_f32_16x16x32_fp8_fp8(a1v0, b0v0, acc[2], 0, 0, 0);
    acc[3] = __builtin_amdgcn_mfma_f32_16x16x32_fp8_fp8(a1v0, b1v0, acc[3], 0, 0, 0);
    acc[0] = __builtin_amdgcn_mfma_f32_16x16x32_fp8_fp8(a0v1, b0v1, acc[0], 0, 0, 0);
    acc[1] = __builtin_amdgcn_mfma_f32_16x16x32_fp8_fp8(a0v1, b1v1, acc[1], 0, 0, 0);
    acc[2] = __builtin_amdgcn_mfma_f32_16x16x32_fp8_fp8(a1v1, b0v1, acc[2], 0, 0, 0);
    acc[3] = __builtin_amdgcn_mfma_f32_16x16x32_fp8_fp8(a1v1, b1v1, acc[3], 0, 0, 0);
    acc[0] = __builtin_amdgcn_mfma_f32_16x16x32_fp8_fp8(a0v2, b0v2, acc[0], 0, 0, 0);
    acc[1] = __builtin_amdgcn_mfma_f32_16x16x32_fp8_fp8(a0v2, b1v2, acc[1], 0, 0, 0);
    acc[2] = __builtin_amdgcn_mfma_f32_16x16x32_fp8_fp8(a1v2, b0v2, acc[2], 0, 0, 0);
    acc[3] = __builtin_amdgcn_mfma_f32_16x16x32_fp8_fp8(a1v2, b1v2, acc[3], 0, 0, 0);
    acc[0] = __builtin_amdgcn_mfma_f32_16x16x32_fp8_fp8(a0v3, b0v3, acc[0], 0, 0, 0);
    acc[1] = __builtin_amdgcn_mfma_f32_16x16x32_fp8_fp8(a0v3, b1v3, acc[1], 0, 0, 0);
    acc[2] = __builtin_amdgcn_mfma_f32_16x16x32_fp8_fp8(a1v3, b0v3, acc[2], 0, 0, 0);
    acc[3] = __builtin_amdgcn_mfma_f32_16x16x32_fp8_fp8(a1v3, b1v3, acc[3], 0, 0, 0);
    __builtin_amdgcn_s_setprio(0);
  };

  const int nIter = 32;
  stage(0); stage(1); stage(2);
  for (int i = 0; i < nIter - 3; ++i) {
    asm volatile("s_waitcnt vmcnt(8)" ::: "memory");
    __builtin_amdgcn_s_barrier();
    stage(i + 3);
    compute(i);
  }
  asm volatile("s_waitcnt vmcnt(8)" ::: "memory");
  __builtin_amdgcn_s_barrier();
  compute(nIter - 3);
  asm volatile("s_waitcnt vmcnt(4)" ::: "memory");
  __builtin_amdgcn_s_barrier();
  compute(nIter - 2);
  asm volatile("s_waitcnt vmcnt(0)" ::: "memory");
  __builtin_amdgcn_s_barrier();
  compute(nIter - 1);

#pragma unroll
  for (int mt = 0; mt < 2; ++mt)
#pragma unroll
    for (int nt = 0; nt < 2; ++nt) {
      int nn = n0 + wn * 32 + nt * 16 + l16;
#pragma unroll
      for (int r = 0; r < 4; ++r) {
        int b = mh * 64 + wm * 32 + mt * 16 + lg * 4 + r;
        float av = acc[mt * 2 + nt][r];
        if (isA) {
          if (nn < 2048) {            // mode 0: eg0 (+ zd update)
            size_t idx = (size_t)b * D0 + nn;
            float zo = c.zd[idx]; float zn = zo - 0.1f * zo + c.x[idx];
            c.zd[idx] = zn;
            c.eg0_bf[idx] = (__bf16)(0.5f * (zn - av));
          } else {                    // mode 2: ed2
            size_t idx = (size_t)b * D2 + (nn - 2048);
            c.ed2_bf[idx] = (__bf16)(0.5f * (c.tr2[idx] - av));
          }
        } else {
          if (nn < 4096) {            // mode 1: eg1
            size_t idx = (size_t)b * D1 + nn;
            c.eg1_bf[idx] = (__bf16)(0.5f * (c.tr1[idx] - av));
          } else {                    // mode 3: ed3 (+ zl update, output)
            size_t idx = (size_t)b * D3 + (nn - 4096);
            float zo = c.zl[idx]; float zn = zo - 0.1f * zo + c.y[idx];
            c.zl[idx] = zn;
            float e = 0.5f * (zn - av);
            c.out[idx] = e; c.ed3_bf[idx] = (__bf16)e;
          }
        }
      }
    }
}

// ================= precomp (bf16 DMA engine, runs once) =================

__global__ __launch_bounds__(256, 2) void precomp_v6(Ctx c) {
  __shared__ __align__(16) __bf16 lsA[4][4096];
  __shared__ __align__(16) __bf16 lsW[4][2048];
  int t = threadIdx.x, w = t >> 6, l = t & 63;
  int l16 = l & 15, lg = l >> 4, wm = w >> 1, wn = w & 1;
  int n0 = blockIdx.x * 32, mh = blockIdx.y;
  f32x4 acc[2];
  f32x4 z4 = {0.f, 0.f, 0.f, 0.f};
  acc[0] = z4; acc[1] = z4;

  Seg segs[2]; int nIter, N; float* outp;
  if (blockIdx.z == 0) {
    segs[0] = { c.x_bf + (size_t)mh * 64 * D0, (unsigned)D0, c.V0n + (size_t)n0 * D0, (unsigned)D0, 32 };
    nIter = 32; N = D1; outp = c.xV0T;
  } else {
    segs[0] = { c.y_bf + (size_t)mh * 64 * D3, (unsigned)D3, c.W2n + (size_t)n0 * D3, (unsigned)D3, 8 };
    nIter = 8; N = D2; outp = c.yW2T;
  }
  segs[1] = segs[0];

  run_gemm(segs, nIter, &lsA[0][0], &lsW[0][0], t, wm, wn, l16, lg, acc);

  int n = n0 + wn * 16 + l16;
#pragma unroll
  for (int mt = 0; mt < 2; ++mt)
#pragma unroll
    for (int r = 0; r < 4; ++r) {
      int b = mh * 64 + wm * 32 + mt * 16 + lg * 4 + r;
      outp[(size_t)b * N + n] = acc[mt][r];
    }
}

// ================= one-shot prep (split into 4 launches via g0) =================

__global__ __launch_bounds__(256) void wprep_kernel(Ctx c, int g0) {
  __shared__ float ls[64][65];
  int g = blockIdx.x + g0;
  const float* src; __bf16* tp = nullptr; uchar* n8 = nullptr; __bf16* nb = nullptr; int R, C;
  if (g < 2048)       { src = c.W0; n8 = c.WA8;                         tp = c.W0t; R = D0; C = D1; }
  else if (g < 6144)  { g -= 2048;  src = c.W1; n8 = c.WB8;             tp = c.W1t; R = D1; C = D2; }
  else if (g < 10240) { g -= 6144;  src = c.V1; n8 = c.WA8 + (size_t)2048 * 4096; tp = c.V1t; R = D2; C = D1; }
  else if (g < 10752) { g -= 10240; src = c.V2; n8 = c.WB8 + (size_t)4096 * 4096; tp = c.V2t; R = D3; C = D2; }
  else if (g < 12800) { g -= 10752; src = c.V0; nb = c.V0n; R = D1; C = D0; }
  else                { g -= 12800; src = c.W2; nb = c.W2n; R = D2; C = D3; }
  int tpr = C / 64;
  int r0 = (g / tpr) * 64, c0 = (g % tpr) * 64;
  int t = threadIdx.x, r = t >> 2, q = t & 3;

  const float4* s4 = reinterpret_cast<const float4*>(src + (size_t)(r0 + r) * C + c0 + q * 16);
  if (n8) {
    int pk[4];
#pragma unroll
    for (int i = 0; i < 4; i++) {
      float4 v = s4[i];
      ls[r][q * 16 + i * 4 + 0] = v.x; ls[r][q * 16 + i * 4 + 1] = v.y;
      ls[r][q * 16 + i * 4 + 2] = v.z; ls[r][q * 16 + i * 4 + 3] = v.w;
      int wd = __builtin_amdgcn_cvt_pk_fp8_f32(v.x, v.y, 0, false);
      wd = __builtin_amdgcn_cvt_pk_fp8_f32(v.z, v.w, wd, true);
      pk[i] = wd;
    }
    int4 pv; pv.x = pk[0]; pv.y = pk[1]; pv.z = pk[2]; pv.w = pk[3];
    *reinterpret_cast<int4*>(n8 + (size_t)(r0 + r) * C + c0 + q * 16) = pv;
    __syncthreads();
    union { __bf16 h[16]; int4 qq[2]; } wv;
#pragma unroll
    for (int i = 0; i < 16; i++) wv.h[i] = (__bf16)ls[q * 16 + i][r];
    int4* dt = reinterpret_cast<int4*>(tp + (size_t)(c0 + r) * R + r0 + q * 16);
    dt[0] = wv.qq[0]; dt[1] = wv.qq[1];
  } else {
    union { __bf16 h[16]; int4 qq[2]; } uu;
#pragma unroll
    for (int i = 0; i < 4; i++) {
      float4 v = s4[i];
      uu.h[i * 4 + 0] = (__bf16)v.x; uu.h[i * 4 + 1] = (__bf16)v.y;
      uu.h[i * 4 + 2] = (__bf16)v.z; uu.h[i * 4 + 3] = (__bf16)v.w;
    }
    int4* dn = reinterpret_cast<int4*>(nb + (size_t)(r0 + r) * C + c0 + q * 16);
    dn[0] = uu.qq[0]; dn[1] = uu.qq[1];
  }
}

// cast x,y -> bf16 AND step-0 "phase2" (s=tr=0): zd=x, zl=y, eg0=.5x, ed3=.5y.
__global__ __launch_bounds__(256) void castinit_kernel(Ctx c) {
  int i = blockIdx.x * 256 + threadIdx.x;
  const int NX = BB * D0 / 4;
  union { __bf16 h[4]; uint2 u; } p, q;
  if (i < NX) {
    float4 xv = reinterpret_cast<const float4*>(c.x)[i];
    reinterpret_cast<float4*>(c.zd)[i] = xv;
    p.h[0] = (__bf16)xv.x; p.h[1] = (__bf16)xv.y; p.h[2] = (__bf16)xv.z; p.h[3] = (__bf16)xv.w;
    reinterpret_cast<uint2*>(c.x_bf)[i] = p.u;
    q.h[0] = (__bf16)(0.5f * xv.x); q.h[1] = (__bf16)(0.5f * xv.y);
    q.h[2] = (__bf16)(0.5f * xv.z); q.h[3] = (__bf16)(0.5f * xv.w);
    reinterpret_cast<uint2*>(c.eg0_bf)[i] = q.u;
  } else {
    int k = i - NX;
    float4 yv = reinterpret_cast<const float4*>(c.y)[k];
    reinterpret_cast<float4*>(c.zl)[k] = yv;
    p.h[0] = (__bf16)yv.x; p.h[1] = (__bf16)yv.y; p.h[2] = (__bf16)yv.z; p.h[3] = (__bf16)yv.w;
    reinterpret_cast<uint2*>(c.y_bf)[k] = p.u;
    q.h[0] = (__bf16)(0.5f * yv.x); q.h[1] = (__bf16)(0.5f * yv.y);
    q.h[2] = (__bf16)(0.5f * yv.z); q.h[3] = (__bf16)(0.5f * yv.w);
    reinterpret_cast<uint2*>(c.ed3_bf)[k] = q.u;
  }
}

// ================= host =================

extern "C" void kernel_launch(void* const* d_in, const int* in_sizes, int n_in,
                              void* d_out, int out_size, void* d_ws, size_t ws_size,
                              hipStream_t stream) {
  Ctx c;
  c.x  = (const float*)d_in[0];
  c.y  = (const float*)d_in[1];
  c.W0 = (const float*)d_in[2];
  c.W1 = (const float*)d_in[3];
  c.W2 = (const float*)d_in[4];
  c.V0 = (const float*)d_in[5];
  c.V1 = (const float*)d_in[6];
  c.V2 = (const float*)d_in[7];
  c.out = (float*)d_out;

  char* p = (char*)d_ws;
  auto af = [&](size_t n) -> float* { float* r = (float*)p; p += ((n * 4 + 255) & ~(size_t)255); return r; };
  auto ah = [&](size_t n) -> __bf16* { __bf16* r = (__bf16*)p; p += ((n * 2 + 255) & ~(size_t)255); return r; };
  auto au = [&](size_t n) -> uchar* { uchar* r = (uchar*)p; p += ((n + 255) & ~(size_t)255); return r; };

  const size_t S1 = (size_t)BB * D1;
  // --- zero-initialized state (memset span) ---
  c.v1 = af(S1); c.j1 = af(S1); c.r1 = af(S1); c.tr1 = af(S1);
  c.v2 = af(S1); c.j2 = af(S1); c.r2 = af(S1); c.tr2 = af(S1);
  c.eg1_bf = ah(S1); c.ed2_bf = ah(S1);
  size_t zero_bytes = (size_t)(p - (char*)d_ws);
  // --- written-before-read buffers ---
  c.zd = af((size_t)BB * D0); c.zl = af((size_t)BB * D3);
  c.xV0T = af(S1); c.yW2T = af(S1);
  c.x_bf = ah((size_t)BB * D0); c.y_bf = ah((size_t)BB * D3);
  c.eg0_bf = ah((size_t)BB * D0); c.ed3_bf = ah((size_t)BB * D3);
  c.s1_f8 = au(S1); c.s2_f8 = au(S1);
  // --- weight copies ---
  c.W0t = ah((size_t)D0 * D1); c.W1t = ah((size_t)D1 * D2); c.V1t = ah((size_t)D2 * D1); c.V2t = ah((size_t)D3 * D2);
  c.V0n = ah((size_t)D1 * D0); c.W2n = ah((size_t)D2 * D3);
  c.WA8 = au((size_t)(D0 + D2) * 4096);   // [W0; V1] rows, K=4096
  c.WB8 = au((size_t)(D1 + D3) * 4096);   // [W1; V2] rows, K=4096

  hipMemsetAsync(d_ws, 0, zero_bytes, stream);
  castinit_kernel<<<320, 256, 0, stream>>>(c);
  // order: phase1-step1 inputs (V1t, W0t) written LAST -> L3-resident at step 1
  wprep_kernel<<<3072, 256, 0, stream>>>(c, 10240);   // V2 + V0 + W2
  wprep_kernel<<<4096, 256, 0, stream>>>(c, 2048);    // W1
  wprep_kernel<<<4096, 256, 0, stream>>>(c, 6144);    // V1
  wprep_kernel<<<2048, 256, 0, stream>>>(c, 0);       // W0
  precomp_v6<<<dim3(128, 2, 2), 256, 0, stream>>>(c);

  for (int s = 1; s < NSTEPS; s++) {
    phase1_v14<<<512, 256, 0, stream>>>(c, 0.5f);
    phase2_v15<<<dim3(168, 2), 256, 0, stream>>>(c);
  }
}